// Round 2
// baseline (616.036 us; speedup 1.0000x reference)
//
#include <hip/hip_runtime.h>
#include <stdint.h>

#define SQ   2048
#define DIN  4096
#define NH   32
#define NKV  8
#define HD   128
#define NQKV 6144

typedef float f32x4 __attribute__((ext_vector_type(4)));
typedef short bf16x8 __attribute__((ext_vector_type(8)));

__device__ __forceinline__ short f2bf(float f) {
  union { float f; uint32_t u; } v; v.f = f;
  uint32_t r = (v.u + 0x7FFFu + ((v.u >> 16) & 1u)) >> 16;
  return (short)r;
}

// async global -> LDS, 16 bytes per lane, dst = lds_base + lane*16 (HW-fixed)
__device__ __forceinline__ void gl2lds(const void* g, void* l) {
  __builtin_amdgcn_global_load_lds(
      (const __attribute__((address_space(1))) void*)g,
      (__attribute__((address_space(3))) void*)l, 16, 0, 0);
}

// ---------------- fp32 -> bf16 elementwise convert ----------------
__global__ void cvt_bf16(const float* __restrict__ src, short* __restrict__ dst, long n) {
  long i = ((long)blockIdx.x * blockDim.x + threadIdx.x) * 4;
  if (i + 3 < n) {
    float4 v = *(const float4*)(src + i);
    short o[4] = { f2bf(v.x), f2bf(v.y), f2bf(v.z), f2bf(v.w) };
    *(uint2*)(dst + i) = *(uint2*)o;
  }
}

// ---------------- tiled transpose + convert: dst[c][r] = src[r][c] ----------------
__global__ __launch_bounds__(256) void transpose_cvt(const float* __restrict__ src, int ldS, long zS,
                                                     short* __restrict__ dst, int ldD, long zD) {
  __shared__ float tile[64][65];
  src += (long)blockIdx.z * zS;
  dst += (long)blockIdx.z * zD;
  int r0 = blockIdx.y * 64, c0 = blockIdx.x * 64;
  int tid = threadIdx.x;
#pragma unroll
  for (int i = 0; i < 16; ++i) {
    int idx = i * 256 + tid;
    int rr = idx >> 6, cc = idx & 63;
    tile[rr][cc] = src[(long)(r0 + rr) * ldS + c0 + cc];
  }
  __syncthreads();
#pragma unroll
  for (int i = 0; i < 16; ++i) {
    int idx = i * 256 + tid;
    int dr = idx >> 6, dc = idx & 63;
    dst[(long)(c0 + dr) * ldD + r0 + dc] = f2bf(tile[dc][dr]);
  }
}

// ---------------- 256x256 8-phase bf16 GEMM (m201 geometry) ----------------
// C(MxN) = A(MxK) * Bt(NxK)^T, fp32 out. BM=BN=256, BK=64, 512 thr = 8 waves
// (2M x 4N), per-wave output 128x64 -> 64 MFMA + 24 ds_read_b128 per K-tile.
// Half-tiles are K-HALVES (256 rows x 32 K = 16 KB, 2 gl2lds/thread each):
//   phase 1: kk0, ncols 0-31   (reads A-kk0 8 frags + B-kk0 j0,j1)  stage S(t+1,A-kk1)
//   phase 2: kk0, ncols 32-63  (reads B-kk0 j2,j3; A reused)        stage S(t+1,B-kk1)
//   phase 3: kk1, ncols 32-63  (reads A-kk1 + B-kk1 j2,j3)          stage S(t+2,A-kk0)
//   phase 4: kk1, ncols 0-31   (reads B-kk1 j0,j1)                  stage S(t+2,B-kk0)
// Each phase: {reads ; 1 half-tile stage ; barrier ; lgkmcnt(0) ; setprio(1)
// 16 MFMA setprio(0) ; barrier}.  Tile boundary: counted vmcnt(4) -- tile t+1
// fully resident, S(t+2,A0/B0) stay in flight.  2 LDS buffers (128 KB).
// Rows are 64 B (4 x 16B chunks); slot = chunk ^ f(row), f(r)=(r&3)^((r>>2)&1)
// -> 2 lanes/bank-quad per b128 quarter-wave (conflict-free).  Staging keeps
// gl2lds dst linear and inverse-swizzles the global source chunk.
#define HBUF  8192    // shorts per K-half (256 rows * 32)
#define BUFSZ 32768   // shorts per buffer (A 2 halves + B 2 halves)
#define MFMA(d, a, b) d = __builtin_amdgcn_mfma_f32_16x16x32_bf16(a, b, d, 0, 0, 0)

#define SA(t, h) { short* d = &lds[(((t) & 1) * BUFSZ) + (h) * HBUF + dA]; \
                   const short* s = aS + (long)(t) * 64 + (h) * 32;        \
                   gl2lds(s, d); gl2lds(s + K16, d + 512); }
#define SB(t, h) { short* d = &lds[(((t) & 1) * BUFSZ) + (h) * HBUF + dB]; \
                   const short* s = bS + (long)(t) * 64 + (h) * 32;        \
                   gl2lds(s, d); gl2lds(s + K16, d + 512); }

__global__ __launch_bounds__(512, 2) void gemm8p(const short* __restrict__ A, const short* __restrict__ Bt,
                                                 float* __restrict__ C, int M, int N, int K) {
  __shared__ __align__(16) short lds[2 * BUFSZ];
  // bijective XCD swizzle (gridDim.x % 8 == 0 at both call sites), M-major in-chunk
  int nwg = gridDim.x;
  int lin = ((int)blockIdx.x & 7) * (nwg >> 3) + ((int)blockIdx.x >> 3);
  int mt = M >> 8;
  int m0 = (lin % mt) << 8, n0 = (lin / mt) << 8;

  int tid = threadIdx.x;
  int w = tid >> 6, lane = tid & 63;
  int l16 = lane & 15, lq = lane >> 4;
  int wm = (w >> 2) << 7;   // 0 / 128
  int wn = (w & 3) << 6;    // 0 / 64 / 128 / 192

  // fragment-read offsets (shorts): row = base + l16, slot = lq ^ f(row);
  // f(row) reduces to a per-lane constant since all row bases are mult of 16.
  int fl = (l16 & 3) ^ ((l16 >> 2) & 1);
  int aoff = (wm + l16) * 32 + ((lq ^ fl) << 3);            // + i*512 + h*HBUF
  int boff = 2 * HBUF + (wn + l16) * 32 + ((lq ^ fl) << 3); // + j*512 + h*HBUF

  // staging: wave w covers rows 32w..32w+31 of each half-tile (2 calls of 16 rows);
  // lane l -> row +(l>>2), LDS slot l&3, global chunk (l&3)^f(l>>2).
  int grow = lane >> 2;
  int gch = (lane & 3) ^ ((grow & 3) ^ ((grow >> 2) & 1));
  const short* aS = A + (long)(m0 + 32 * w + grow) * K + gch * 8;
  const short* bS = Bt + (long)(n0 + 32 * w + grow) * K + gch * 8;
  long K16 = 16L * K;
  int dA = 1024 * w;
  int dB = 2 * HBUF + 1024 * w;

  f32x4 acc[8][4] = {};
  const int KT = K >> 6;

  // ---- prologue: tile 0 fully + tile 1 kk0-halves ----
  SA(0, 0); SB(0, 0); SA(0, 1); SB(0, 1); SA(1, 0); SB(1, 0);
  asm volatile("s_waitcnt vmcnt(4)" ::: "memory");   // tile 0 resident; S(1,*k0) in flight
  __builtin_amdgcn_s_barrier();

  for (int t = 0; t < KT; ++t) {
    const short* buf = &lds[(t & 1) * BUFSZ];
    bool s1 = (t + 1 < KT), s2 = (t + 2 < KT);
    bf16x8 af[8], bfr[4];

    // ---- phase 1: kk0 x j01 ----
#pragma unroll
    for (int i = 0; i < 8; ++i) af[i] = *(const bf16x8*)&buf[aoff + i * 512];
    bfr[0] = *(const bf16x8*)&buf[boff];
    bfr[1] = *(const bf16x8*)&buf[boff + 512];
    if (s1) SA(t + 1, 1);
    __builtin_amdgcn_s_barrier();
    asm volatile("s_waitcnt lgkmcnt(0)" ::: "memory");
    __builtin_amdgcn_s_setprio(1);
#pragma unroll
    for (int i = 0; i < 8; ++i) { MFMA(acc[i][0], af[i], bfr[0]); MFMA(acc[i][1], af[i], bfr[1]); }
    __builtin_amdgcn_s_setprio(0);
    __builtin_amdgcn_s_barrier();

    // ---- phase 2: kk0 x j23 ----
    bfr[2] = *(const bf16x8*)&buf[boff + 1024];
    bfr[3] = *(const bf16x8*)&buf[boff + 1536];
    if (s1) SB(t + 1, 1);
    __builtin_amdgcn_s_barrier();
    asm volatile("s_waitcnt lgkmcnt(0)" ::: "memory");
    __builtin_amdgcn_s_setprio(1);
#pragma unroll
    for (int i = 0; i < 8; ++i) { MFMA(acc[i][2], af[i], bfr[2]); MFMA(acc[i][3], af[i], bfr[3]); }
    __builtin_amdgcn_s_setprio(0);
    __builtin_amdgcn_s_barrier();

    // ---- phase 3: kk1 x j23 ----
#pragma unroll
    for (int i = 0; i < 8; ++i) af[i] = *(const bf16x8*)&buf[HBUF + aoff + i * 512];
    bfr[2] = *(const bf16x8*)&buf[HBUF + boff + 1024];
    bfr[3] = *(const bf16x8*)&buf[HBUF + boff + 1536];
    if (s2) SA(t + 2, 0);
    __builtin_amdgcn_s_barrier();
    asm volatile("s_waitcnt lgkmcnt(0)" ::: "memory");
    __builtin_amdgcn_s_setprio(1);
#pragma unroll
    for (int i = 0; i < 8; ++i) { MFMA(acc[i][2], af[i], bfr[2]); MFMA(acc[i][3], af[i], bfr[3]); }
    __builtin_amdgcn_s_setprio(0);
    __builtin_amdgcn_s_barrier();

    // ---- phase 4: kk1 x j01 ; K-tile boundary ----
    bfr[0] = *(const bf16x8*)&buf[HBUF + boff];
    bfr[1] = *(const bf16x8*)&buf[HBUF + boff + 512];
    if (s2) SB(t + 2, 0);
    __builtin_amdgcn_s_barrier();
    asm volatile("s_waitcnt lgkmcnt(0)" ::: "memory");
    __builtin_amdgcn_s_setprio(1);
#pragma unroll
    for (int i = 0; i < 8; ++i) { MFMA(acc[i][0], af[i], bfr[0]); MFMA(acc[i][1], af[i], bfr[1]); }
    __builtin_amdgcn_s_setprio(0);
    if (t < KT - 1) {
      if (t == KT - 2) asm volatile("s_waitcnt vmcnt(0)" ::: "memory");  // last boundary: drain
      else             asm volatile("s_waitcnt vmcnt(4)" ::: "memory");  // tile t+1 resident; t+2 k0 flying
      __builtin_amdgcn_s_barrier();
    }
  }

  // ---- epilogue: C-write (col=lane&15, row=(lane>>4)*4+reg) ----
#pragma unroll
  for (int i = 0; i < 8; ++i)
#pragma unroll
    for (int j = 0; j < 4; ++j)
#pragma unroll
      for (int r = 0; r < 4; ++r)
        C[(long)(m0 + wm + i * 16 + lq * 4 + r) * N + n0 + wn + j * 16 + l16] = acc[i][j][r];
}

// ---------------- fused LayerNorm + RoPE ----------------
__global__ __launch_bounds__(64) void ln_rope(const float* __restrict__ qkv,
                                              const float* __restrict__ cosb, const float* __restrict__ sinb,
                                              const float* __restrict__ qw, const float* __restrict__ qb,
                                              const float* __restrict__ kw, const float* __restrict__ kb,
                                              short* __restrict__ qo, short* __restrict__ ko) {
  int s = blockIdx.x, slice = blockIdx.y, t = threadIdx.x;
  bool isq = slice < NH;
  int off = isq ? slice * HD : DIN + (slice - NH) * HD;
  const float* src = qkv + (long)s * NQKV + off;
  float v0 = src[t], v1 = src[t + 64];
  float sum = v0 + v1, ss = v0 * v0 + v1 * v1;
#pragma unroll
  for (int o = 1; o < 64; o <<= 1) { sum += __shfl_xor(sum, o); ss += __shfl_xor(ss, o); }
  float mu = sum * (1.f / 128.f);
  float var = ss * (1.f / 128.f) - mu * mu;
  float rstd = rsqrtf(var + 1e-6f);
  const float* w  = isq ? qw : kw;
  const float* bb = isq ? qb : kb;
  float n0 = (v0 - mu) * rstd * w[t]      + bb[t];
  float n1 = (v1 - mu) * rstd * w[t + 64] + bb[t + 64];
  float c0 = cosb[s * HD + t], c1 = cosb[s * HD + t + 64];
  float s0 = sinb[s * HD + t], s1 = sinb[s * HD + t + 64];
  float o0 = n0 * c0 - n1 * s0;
  float o1 = n1 * c1 + n0 * s1;
  short* dst = isq ? (qo + ((long)slice * SQ + s) * HD)
                   : (ko + ((long)(slice - NH) * SQ + s) * HD);
  dst[t] = f2bf(o0);
  dst[t + 64] = f2bf(o1);
}

// ---------------- flash attention, LDS-staged K/V, causal-paired ----------------
__global__ __launch_bounds__(256) void attn(const short* __restrict__ q, const short* __restrict__ k,
                                            const short* __restrict__ vT, short* __restrict__ ctx) {
  int pair = blockIdx.x, h = blockIdx.y, g = h >> 2;
  int tid = threadIdx.x, w = tid >> 6, lane = tid & 63;
  int l16 = lane & 15, lq = lane >> 4;
  __shared__ __align__(16) short Ks[64 * 128];    // 16 KB: [key][128], chunk16 ^ (key&15)
  __shared__ __align__(16) short Vs[128 * 64];    // 16 KB: [d][64],   chunk8  ^ (d&7)
  __shared__ __align__(16) short pbuf[4][16 * 72];
  const short* qh = q + (long)h * SQ * HD;
  const short* kg = k + (long)g * SQ * HD;
  const short* vg = vT + (long)g * HD * SQ;
  int kr = (w * 4) * 4 + (lane >> 4);
  int vrw = (w * 4) * 8 + (lane >> 3);
  const float sc = 0.08838834764831845f * 1.4426950408889634f;  // 1/sqrt(128) * log2(e)

  for (int st = 0; st < 2; ++st) {
    int qt = st ? (31 - pair) : pair;
    int qbase = qt * 64 + w * 16;
    bf16x8 aq[4];
#pragma unroll
    for (int kk = 0; kk < 4; ++kk)
      aq[kk] = *(const bf16x8*)&qh[(long)(qbase + l16) * HD + kk * 32 + lq * 8];
    float m_r[4], l_r[4];
    f32x4 acc[8] = {};
#pragma unroll
    for (int r = 0; r < 4; ++r) { m_r[r] = -__builtin_inff(); l_r[r] = 0.f; }

    for (int kt = 0; kt <= qt; ++kt) {
#pragma unroll
      for (int j = 0; j < 4; ++j) {
        int call = w * 4 + j;
        int r = kr + j * 4;
        int chk = (lane & 15) ^ (r & 15);
        gl2lds(&kg[(long)(kt * 64 + r) * HD + chk * 8], &Ks[call * 512]);
        int rv = vrw + j * 8;
        int chv = (lane & 7) ^ (rv & 7);
        gl2lds(&vg[(long)rv * SQ + kt * 64 + chv * 8], &Vs[call * 512]);
      }
      __syncthreads();
      f32x4 s4[4];
#pragma unroll
      for (int b = 0; b < 4; ++b) s4[b] = (f32x4){0.f, 0.f, 0.f, 0.f};
#pragma unroll
      for (int b = 0; b < 4; ++b) {
        int krow = b * 16 + l16;
#pragma unroll
        for (int kk = 0; kk < 4; ++kk) {
          bf16x8 bk = *(const bf16x8*)&Ks[krow * 128 + ((kk * 4 + lq) ^ (krow & 15)) * 8];
          s4[b] = __builtin_amdgcn_mfma_f32_16x16x32_bf16(aq[kk], bk, s4[b], 0, 0, 0);
        }
      }
      int qrow0 = qbase + lq * 4;
#pragma unroll
      for (int b = 0; b < 4; ++b) {
        int key = kt * 64 + b * 16 + l16;
#pragma unroll
        for (int r = 0; r < 4; ++r) {
          float val = s4[b][r] * sc;
          s4[b][r] = (key > qrow0 + r) ? -__builtin_inff() : val;
        }
      }
      float p[4][4];
#pragma unroll
      for (int r = 0; r < 4; ++r) {
        float mx = fmaxf(fmaxf(s4[0][r], s4[1][r]), fmaxf(s4[2][r], s4[3][r]));
#pragma unroll
        for (int o = 1; o < 16; o <<= 1) mx = fmaxf(mx, __shfl_xor(mx, o));
        float mnew = fmaxf(m_r[r], mx);
        float alpha = exp2f(m_r[r] - mnew);
        float sum = 0.f;
#pragma unroll
        for (int b = 0; b < 4; ++b) { float pv = exp2f(s4[b][r] - mnew); p[b][r] = pv; sum += pv; }
#pragma unroll
        for (int o = 1; o < 16; o <<= 1) sum += __shfl_xor(sum, o);
        l_r[r] = l_r[r] * alpha + sum;
        m_r[r] = mnew;
#pragma unroll
        for (int n = 0; n < 8; ++n) acc[n][r] *= alpha;
      }
#pragma unroll
      for (int b = 0; b < 4; ++b)
#pragma unroll
        for (int r = 0; r < 4; ++r)
          pbuf[w][(lq * 4 + r) * 72 + b * 16 + l16] = f2bf(p[b][r]);
#pragma unroll
      for (int kk = 0; kk < 2; ++kk) {
        bf16x8 pf = *(const bf16x8*)&pbuf[w][l16 * 72 + kk * 32 + lq * 8];
#pragma unroll
        for (int n = 0; n < 8; ++n) {
          int vrow = n * 16 + l16;
          bf16x8 vf = *(const bf16x8*)&Vs[vrow * 64 + ((kk * 4 + lq) ^ (vrow & 7)) * 8];
          acc[n] = __builtin_amdgcn_mfma_f32_16x16x32_bf16(pf, vf, acc[n], 0, 0, 0);
        }
      }
      __syncthreads();
    }
#pragma unroll
    for (int n = 0; n < 8; ++n)
#pragma unroll
      for (int r = 0; r < 4; ++r) {
        int srow = qbase + lq * 4 + r;
        ctx[(long)srow * (NH * HD) + h * HD + n * 16 + l16] = f2bf(acc[n][r] / l_r[r]);
      }
  }
}

// ---------------- workspace layout ----------------
#define XB_OFF     0L
#define QR_OFF     0L
#define WQKVT_OFF  16777216L
#define KR_OFF     16777216L
#define VT_OFF     20971520L
#define CTX_OFF    25165824L
#define WOT_OFF    67108864L
#define QKV_OFF    100663296L

extern "C" void kernel_launch(void* const* d_in, const int* in_sizes, int n_in,
                              void* d_out, int out_size, void* d_ws, size_t ws_size,
                              hipStream_t stream) {
  const float* x    = (const float*)d_in[0];
  const float* cosb = (const float*)d_in[2];
  const float* sinb = (const float*)d_in[3];
  const float* Wq   = (const float*)d_in[4];
  const float* Wk   = (const float*)d_in[5];
  const float* Wv   = (const float*)d_in[6];
  const float* Wo   = (const float*)d_in[7];
  const float* qnw  = (const float*)d_in[8];
  const float* qnb  = (const float*)d_in[9];
  const float* knw  = (const float*)d_in[10];
  const float* knb  = (const float*)d_in[11];

  char* ws = (char*)d_ws;
  short* xb    = (short*)(ws + XB_OFF);
  short* qr    = (short*)(ws + QR_OFF);
  short* wqkvt = (short*)(ws + WQKVT_OFF);
  short* krp   = (short*)(ws + KR_OFF);
  short* vt    = (short*)(ws + VT_OFF);
  short* ctx   = (short*)(ws + CTX_OFF);
  short* wot   = (short*)(ws + WOT_OFF);
  float* qkv   = (float*)(ws + QKV_OFF);

  cvt_bf16<<<8192, 256, 0, stream>>>(x, xb, (long)SQ * DIN);
  transpose_cvt<<<dim3(64, 64, 1), 256, 0, stream>>>(Wq, 4096, 0L, wqkvt, 4096, 0L);
  transpose_cvt<<<dim3(16, 64, 1), 256, 0, stream>>>(Wk, 1024, 0L, wqkvt + (long)4096 * 4096, 4096, 0L);
  transpose_cvt<<<dim3(16, 64, 1), 256, 0, stream>>>(Wv, 1024, 0L, wqkvt + (long)5120 * 4096, 4096, 0L);
  transpose_cvt<<<dim3(64, 64, 1), 256, 0, stream>>>(Wo, 4096, 0L, wot, 4096, 0L);
  gemm8p<<<(SQ / 256) * (NQKV / 256), 512, 0, stream>>>(xb, wqkvt, qkv, SQ, NQKV, DIN);
  ln_rope<<<dim3(SQ, NH + NKV), 64, 0, stream>>>(qkv, cosb, sinb, qnw, qnb, knw, knb, qr, krp);
  transpose_cvt<<<dim3(2, 32, 8), 256, 0, stream>>>(qkv + 5120, NQKV, 128L, vt, SQ, (long)HD * SQ);
  attn<<<dim3(16, NH), 256, 0, stream>>>(qr, krp, vt, ctx);
  gemm8p<<<(SQ / 256) * (DIN / 256), 512, 0, stream>>>(ctx, wot, (float*)d_out, SQ, DIN, DIN);
}

// Round 3
// 598.371 us; speedup vs baseline: 1.0295x; 1.0295x over previous
//
#include <hip/hip_runtime.h>
#include <stdint.h>

#define SQ   2048
#define DIN  4096
#define NH   32
#define NKV  8
#define HD   128
#define NQKV 6144

typedef float f32x4 __attribute__((ext_vector_type(4)));
typedef short bf16x8 __attribute__((ext_vector_type(8)));

__device__ __forceinline__ short f2bf(float f) {
  union { float f; uint32_t u; } v; v.f = f;
  uint32_t r = (v.u + 0x7FFFu + ((v.u >> 16) & 1u)) >> 16;
  return (short)r;
}

// async global -> LDS, 16 bytes per lane, dst = lds_base + lane*16 (HW-fixed)
__device__ __forceinline__ void gl2lds(const void* g, void* l) {
  __builtin_amdgcn_global_load_lds(
      (const __attribute__((address_space(1))) void*)g,
      (__attribute__((address_space(3))) void*)l, 16, 0, 0);
}

// ---------------- fp32 -> bf16 elementwise convert ----------------
__global__ void cvt_bf16(const float* __restrict__ src, short* __restrict__ dst, long n) {
  long i = ((long)blockIdx.x * blockDim.x + threadIdx.x) * 4;
  if (i + 3 < n) {
    float4 v = *(const float4*)(src + i);
    short o[4] = { f2bf(v.x), f2bf(v.y), f2bf(v.z), f2bf(v.w) };
    *(uint2*)(dst + i) = *(uint2*)o;
  }
}

// ---------------- tiled transpose + convert: dst[c][r] = src[r][c] ----------------
__global__ __launch_bounds__(256) void transpose_cvt(const float* __restrict__ src, int ldS, long zS,
                                                     short* __restrict__ dst, int ldD, long zD) {
  __shared__ float tile[64][65];
  src += (long)blockIdx.z * zS;
  dst += (long)blockIdx.z * zD;
  int r0 = blockIdx.y * 64, c0 = blockIdx.x * 64;
  int tid = threadIdx.x;
#pragma unroll
  for (int i = 0; i < 16; ++i) {
    int idx = i * 256 + tid;
    int rr = idx >> 6, cc = idx & 63;
    tile[rr][cc] = src[(long)(r0 + rr) * ldS + c0 + cc];
  }
  __syncthreads();
#pragma unroll
  for (int i = 0; i < 16; ++i) {
    int idx = i * 256 + tid;
    int dr = idx >> 6, dc = idx & 63;
    dst[(long)(c0 + dr) * ldD + r0 + dc] = f2bf(tile[dc][dr]);
  }
}

// ---------------- 256x256 4-phase bf16 GEMM, conflict-free LDS ----------------
// C(MxN) = A(MxK) * Bt(NxK)^T, fp32 out. BM=BN=256, BK=64, 512 thr = 8 waves
// (2M x 4N), per-wave output 128x64 -> 64 MFMA + 24 ds_read_b128 per K-tile,
// 16 MFMA per barrier-pair (4 phases/K-tile).
// LDS rows are FULL BK=64 bf16 (128 B = 8 x 16B chunks), slot = chunk^(row&7)
// (round-1-verified: 0 bank conflicts on b128 frag reads). Staging keeps
// gl2lds dst linear (1KB wave-calls = 8 rows) and inverse-swizzles the
// global source chunk: lane l fetches chunk (l&7)^((l>>3)&7).
// Pipeline: 2 buffers (128 KB). ALL 8 loads for tile t+1 are issued in
// phases 1-2 of tile t (target buffer was fully consumed at end of t-1;
// boundary barrier orders t-1 ph4 reads before these writes). Boundary
// vmcnt(0) thus has ~3 phases (~1800 cyc) of lead -> no drain stall.
#define ASZ   16384   // shorts: A panel per buffer (256 rows x 64)
#define BUFSZ 32768   // shorts per buffer (A + B)
#define MFMA(d, a, b) d = __builtin_amdgcn_mfma_f32_16x16x32_bf16(a, b, d, 0, 0, 0)

#define SA(t) { short* d = &lds[(((t) & 1) * BUFSZ) + dA]; const short* s = aS + (long)(t) * 64; \
                gl2lds(s, d); gl2lds(s + K8, d + 512); gl2lds(s + 2 * K8, d + 1024); gl2lds(s + 3 * K8, d + 1536); }
#define SB(t) { short* d = &lds[(((t) & 1) * BUFSZ) + dB]; const short* s = bS + (long)(t) * 64; \
                gl2lds(s, d); gl2lds(s + K8, d + 512); gl2lds(s + 2 * K8, d + 1024); gl2lds(s + 3 * K8, d + 1536); }

__global__ __launch_bounds__(512, 2) void gemm8p(const short* __restrict__ A, const short* __restrict__ Bt,
                                                 float* __restrict__ C, int M, int N, int K) {
  __shared__ __align__(16) short lds[2 * BUFSZ];
  // bijective XCD swizzle (gridDim.x % 8 == 0 at both call sites), M-major in-chunk
  int nwg = gridDim.x;
  int lin = ((int)blockIdx.x & 7) * (nwg >> 3) + ((int)blockIdx.x >> 3);
  int mt = M >> 8;
  int m0 = (lin % mt) << 8, n0 = (lin / mt) << 8;

  int tid = threadIdx.x;
  int w = tid >> 6, lane = tid & 63;
  int l16 = lane & 15, lq = lane >> 4;
  int wm = (w >> 2) << 7;   // 0 / 128
  int wn = (w & 3) << 6;    // 0 / 64 / 128 / 192

  // fragment-read offsets (shorts): row = base + l16 (base mult of 16),
  // chunk = kk*4+lq, slot = chunk ^ (l16&7).
  int s7 = l16 & 7;
  int fo0 = ((lq ^ s7) << 3);          // kk0
  int fo1 = (((lq + 4) ^ s7) << 3);    // kk1
  int arow = (wm + l16) * 64;          // + i*1024
  int brow = ASZ + (wn + l16) * 64;    // + j*1024

  // staging: wave w covers rows 32w..32w+31 of each operand (4 calls of 8 rows);
  // lane l -> row +(l>>3), LDS slot l&7, global chunk (l&7)^((l>>3)&7).
  int srow = lane >> 3;
  int gch = (lane & 7) ^ srow;
  const short* aS = A + (long)(m0 + 32 * w + srow) * K + gch * 8;
  const short* bS = Bt + (long)(n0 + 32 * w + srow) * K + gch * 8;
  long K8 = 8L * K;
  int dA = (32 * w) * 64;
  int dB = ASZ + (32 * w) * 64;

  f32x4 acc[8][4] = {};
  const int KT = K >> 6;

  // ---- prologue: stage tile 0 ----
  SA(0); SB(0);
  asm volatile("s_waitcnt vmcnt(0)" ::: "memory");
  __builtin_amdgcn_s_barrier();

  for (int t = 0; t < KT; ++t) {
    const short* buf = &lds[(t & 1) * BUFSZ];
    bool s1 = (t + 1 < KT);
    bf16x8 af[8], b0, b1;

    // ---- phase 1: kk0 x j01 ; issue A(t+1) ----
#pragma unroll
    for (int i = 0; i < 8; ++i) af[i] = *(const bf16x8*)&buf[arow + i * 1024 + fo0];
    b0 = *(const bf16x8*)&buf[brow + fo0];
    b1 = *(const bf16x8*)&buf[brow + 1024 + fo0];
    if (s1) SA(t + 1);
    __builtin_amdgcn_s_barrier();
    asm volatile("s_waitcnt lgkmcnt(0)" ::: "memory");
    __builtin_amdgcn_s_setprio(1);
#pragma unroll
    for (int i = 0; i < 8; ++i) { MFMA(acc[i][0], af[i], b0); MFMA(acc[i][1], af[i], b1); }
    __builtin_amdgcn_s_setprio(0);
    __builtin_amdgcn_s_barrier();

    // ---- phase 2: kk0 x j23 ; issue B(t+1) ----
    b0 = *(const bf16x8*)&buf[brow + 2048 + fo0];
    b1 = *(const bf16x8*)&buf[brow + 3072 + fo0];
    if (s1) SB(t + 1);
    __builtin_amdgcn_s_barrier();
    asm volatile("s_waitcnt lgkmcnt(0)" ::: "memory");
    __builtin_amdgcn_s_setprio(1);
#pragma unroll
    for (int i = 0; i < 8; ++i) { MFMA(acc[i][2], af[i], b0); MFMA(acc[i][3], af[i], b1); }
    __builtin_amdgcn_s_setprio(0);
    __builtin_amdgcn_s_barrier();

    // ---- phase 3: kk1 x j23 ----
#pragma unroll
    for (int i = 0; i < 8; ++i) af[i] = *(const bf16x8*)&buf[arow + i * 1024 + fo1];
    b0 = *(const bf16x8*)&buf[brow + 2048 + fo1];
    b1 = *(const bf16x8*)&buf[brow + 3072 + fo1];
    __builtin_amdgcn_s_barrier();
    asm volatile("s_waitcnt lgkmcnt(0)" ::: "memory");
    __builtin_amdgcn_s_setprio(1);
#pragma unroll
    for (int i = 0; i < 8; ++i) { MFMA(acc[i][2], af[i], b0); MFMA(acc[i][3], af[i], b1); }
    __builtin_amdgcn_s_setprio(0);
    __builtin_amdgcn_s_barrier();

    // ---- phase 4: kk1 x j01 ; K-tile boundary ----
    b0 = *(const bf16x8*)&buf[brow + fo1];
    b1 = *(const bf16x8*)&buf[brow + 1024 + fo1];
    __builtin_amdgcn_s_barrier();
    asm volatile("s_waitcnt lgkmcnt(0)" ::: "memory");
    __builtin_amdgcn_s_setprio(1);
#pragma unroll
    for (int i = 0; i < 8; ++i) { MFMA(acc[i][0], af[i], b0); MFMA(acc[i][1], af[i], b1); }
    __builtin_amdgcn_s_setprio(0);
    if (s1) {
      asm volatile("s_waitcnt vmcnt(0)" ::: "memory");   // ~3-phase lead: no drain stall
      __builtin_amdgcn_s_barrier();
    }
  }

  // ---- epilogue: C-write (col=lane&15, row=(lane>>4)*4+reg) ----
#pragma unroll
  for (int i = 0; i < 8; ++i)
#pragma unroll
    for (int j = 0; j < 4; ++j)
#pragma unroll
      for (int r = 0; r < 4; ++r)
        C[(long)(m0 + wm + i * 16 + lq * 4 + r) * N + n0 + wn + j * 16 + l16] = acc[i][j][r];
}

// ---------------- fused LayerNorm + RoPE ----------------
__global__ __launch_bounds__(64) void ln_rope(const float* __restrict__ qkv,
                                              const float* __restrict__ cosb, const float* __restrict__ sinb,
                                              const float* __restrict__ qw, const float* __restrict__ qb,
                                              const float* __restrict__ kw, const float* __restrict__ kb,
                                              short* __restrict__ qo, short* __restrict__ ko) {
  int s = blockIdx.x, slice = blockIdx.y, t = threadIdx.x;
  bool isq = slice < NH;
  int off = isq ? slice * HD : DIN + (slice - NH) * HD;
  const float* src = qkv + (long)s * NQKV + off;
  float v0 = src[t], v1 = src[t + 64];
  float sum = v0 + v1, ss = v0 * v0 + v1 * v1;
#pragma unroll
  for (int o = 1; o < 64; o <<= 1) { sum += __shfl_xor(sum, o); ss += __shfl_xor(ss, o); }
  float mu = sum * (1.f / 128.f);
  float var = ss * (1.f / 128.f) - mu * mu;
  float rstd = rsqrtf(var + 1e-6f);
  const float* w  = isq ? qw : kw;
  const float* bb = isq ? qb : kb;
  float n0 = (v0 - mu) * rstd * w[t]      + bb[t];
  float n1 = (v1 - mu) * rstd * w[t + 64] + bb[t + 64];
  float c0 = cosb[s * HD + t], c1 = cosb[s * HD + t + 64];
  float s0 = sinb[s * HD + t], s1 = sinb[s * HD + t + 64];
  float o0 = n0 * c0 - n1 * s0;
  float o1 = n1 * c1 + n0 * s1;
  short* dst = isq ? (qo + ((long)slice * SQ + s) * HD)
                   : (ko + ((long)(slice - NH) * SQ + s) * HD);
  dst[t] = f2bf(o0);
  dst[t + 64] = f2bf(o1);
}

// ---------------- flash attention, LDS-staged K/V, causal-paired ----------------
__global__ __launch_bounds__(256) void attn(const short* __restrict__ q, const short* __restrict__ k,
                                            const short* __restrict__ vT, short* __restrict__ ctx) {
  int pair = blockIdx.x, h = blockIdx.y, g = h >> 2;
  int tid = threadIdx.x, w = tid >> 6, lane = tid & 63;
  int l16 = lane & 15, lq = lane >> 4;
  __shared__ __align__(16) short Ks[64 * 128];    // 16 KB: [key][128], chunk16 ^ (key&15)
  __shared__ __align__(16) short Vs[128 * 64];    // 16 KB: [d][64],   chunk8  ^ (d&7)
  __shared__ __align__(16) short pbuf[4][16 * 72];
  const short* qh = q + (long)h * SQ * HD;
  const short* kg = k + (long)g * SQ * HD;
  const short* vg = vT + (long)g * HD * SQ;
  int kr = (w * 4) * 4 + (lane >> 4);
  int vrw = (w * 4) * 8 + (lane >> 3);
  const float sc = 0.08838834764831845f * 1.4426950408889634f;  // 1/sqrt(128) * log2(e)

  for (int st = 0; st < 2; ++st) {
    int qt = st ? (31 - pair) : pair;
    int qbase = qt * 64 + w * 16;
    bf16x8 aq[4];
#pragma unroll
    for (int kk = 0; kk < 4; ++kk)
      aq[kk] = *(const bf16x8*)&qh[(long)(qbase + l16) * HD + kk * 32 + lq * 8];
    float m_r[4], l_r[4];
    f32x4 acc[8] = {};
#pragma unroll
    for (int r = 0; r < 4; ++r) { m_r[r] = -__builtin_inff(); l_r[r] = 0.f; }

    for (int kt = 0; kt <= qt; ++kt) {
#pragma unroll
      for (int j = 0; j < 4; ++j) {
        int call = w * 4 + j;
        int r = kr + j * 4;
        int chk = (lane & 15) ^ (r & 15);
        gl2lds(&kg[(long)(kt * 64 + r) * HD + chk * 8], &Ks[call * 512]);
        int rv = vrw + j * 8;
        int chv = (lane & 7) ^ (rv & 7);
        gl2lds(&vg[(long)rv * SQ + kt * 64 + chv * 8], &Vs[call * 512]);
      }
      __syncthreads();
      f32x4 s4[4];
#pragma unroll
      for (int b = 0; b < 4; ++b) s4[b] = (f32x4){0.f, 0.f, 0.f, 0.f};
#pragma unroll
      for (int b = 0; b < 4; ++b) {
        int krow = b * 16 + l16;
#pragma unroll
        for (int kk = 0; kk < 4; ++kk) {
          bf16x8 bk = *(const bf16x8*)&Ks[krow * 128 + ((kk * 4 + lq) ^ (krow & 15)) * 8];
          s4[b] = __builtin_amdgcn_mfma_f32_16x16x32_bf16(aq[kk], bk, s4[b], 0, 0, 0);
        }
      }
      int qrow0 = qbase + lq * 4;
#pragma unroll
      for (int b = 0; b < 4; ++b) {
        int key = kt * 64 + b * 16 + l16;
#pragma unroll
        for (int r = 0; r < 4; ++r) {
          float val = s4[b][r] * sc;
          s4[b][r] = (key > qrow0 + r) ? -__builtin_inff() : val;
        }
      }
      float p[4][4];
#pragma unroll
      for (int r = 0; r < 4; ++r) {
        float mx = fmaxf(fmaxf(s4[0][r], s4[1][r]), fmaxf(s4[2][r], s4[3][r]));
#pragma unroll
        for (int o = 1; o < 16; o <<= 1) mx = fmaxf(mx, __shfl_xor(mx, o));
        float mnew = fmaxf(m_r[r], mx);
        float alpha = exp2f(m_r[r] - mnew);
        float sum = 0.f;
#pragma unroll
        for (int b = 0; b < 4; ++b) { float pv = exp2f(s4[b][r] - mnew); p[b][r] = pv; sum += pv; }
#pragma unroll
        for (int o = 1; o < 16; o <<= 1) sum += __shfl_xor(sum, o);
        l_r[r] = l_r[r] * alpha + sum;
        m_r[r] = mnew;
#pragma unroll
        for (int n = 0; n < 8; ++n) acc[n][r] *= alpha;
      }
#pragma unroll
      for (int b = 0; b < 4; ++b)
#pragma unroll
        for (int r = 0; r < 4; ++r)
          pbuf[w][(lq * 4 + r) * 72 + b * 16 + l16] = f2bf(p[b][r]);
#pragma unroll
      for (int kk = 0; kk < 2; ++kk) {
        bf16x8 pf = *(const bf16x8*)&pbuf[w][l16 * 72 + kk * 32 + lq * 8];
#pragma unroll
        for (int n = 0; n < 8; ++n) {
          int vrow = n * 16 + l16;
          bf16x8 vf = *(const bf16x8*)&Vs[vrow * 64 + ((kk * 4 + lq) ^ (vrow & 7)) * 8];
          acc[n] = __builtin_amdgcn_mfma_f32_16x16x32_bf16(pf, vf, acc[n], 0, 0, 0);
        }
      }
      __syncthreads();
    }
#pragma unroll
    for (int n = 0; n < 8; ++n)
#pragma unroll
      for (int r = 0; r < 4; ++r) {
        int srow = qbase + lq * 4 + r;
        ctx[(long)srow * (NH * HD) + h * HD + n * 16 + l16] = f2bf(acc[n][r] / l_r[r]);
      }
  }
}

// ---------------- workspace layout ----------------
#define XB_OFF     0L
#define QR_OFF     0L
#define WQKVT_OFF  16777216L
#define KR_OFF     16777216L
#define VT_OFF     20971520L
#define CTX_OFF    25165824L
#define WOT_OFF    67108864L
#define QKV_OFF    100663296L

extern "C" void kernel_launch(void* const* d_in, const int* in_sizes, int n_in,
                              void* d_out, int out_size, void* d_ws, size_t ws_size,
                              hipStream_t stream) {
  const float* x    = (const float*)d_in[0];
  const float* cosb = (const float*)d_in[2];
  const float* sinb = (const float*)d_in[3];
  const float* Wq   = (const float*)d_in[4];
  const float* Wk   = (const float*)d_in[5];
  const float* Wv   = (const float*)d_in[6];
  const float* Wo   = (const float*)d_in[7];
  const float* qnw  = (const float*)d_in[8];
  const float* qnb  = (const float*)d_in[9];
  const float* knw  = (const float*)d_in[10];
  const float* knb  = (const float*)d_in[11];

  char* ws = (char*)d_ws;
  short* xb    = (short*)(ws + XB_OFF);
  short* qr    = (short*)(ws + QR_OFF);
  short* wqkvt = (short*)(ws + WQKVT_OFF);
  short* krp   = (short*)(ws + KR_OFF);
  short* vt    = (short*)(ws + VT_OFF);
  short* ctx   = (short*)(ws + CTX_OFF);
  short* wot   = (short*)(ws + WOT_OFF);
  float* qkv   = (float*)(ws + QKV_OFF);

  cvt_bf16<<<8192, 256, 0, stream>>>(x, xb, (long)SQ * DIN);
  transpose_cvt<<<dim3(64, 64, 1), 256, 0, stream>>>(Wq, 4096, 0L, wqkvt, 4096, 0L);
  transpose_cvt<<<dim3(16, 64, 1), 256, 0, stream>>>(Wk, 1024, 0L, wqkvt + (long)4096 * 4096, 4096, 0L);
  transpose_cvt<<<dim3(16, 64, 1), 256, 0, stream>>>(Wv, 1024, 0L, wqkvt + (long)5120 * 4096, 4096, 0L);
  transpose_cvt<<<dim3(64, 64, 1), 256, 0, stream>>>(Wo, 4096, 0L, wot, 4096, 0L);
  gemm8p<<<(SQ / 256) * (NQKV / 256), 512, 0, stream>>>(xb, wqkvt, qkv, SQ, NQKV, DIN);
  ln_rope<<<dim3(SQ, NH + NKV), 64, 0, stream>>>(qkv, cosb, sinb, qnw, qnb, knw, knb, qr, krp);
  transpose_cvt<<<dim3(2, 32, 8), 256, 0, stream>>>(qkv + 5120, NQKV, 128L, vt, SQ, (long)HD * SQ);
  attn<<<dim3(16, NH), 256, 0, stream>>>(qr, krp, vt, ctx);
  gemm8p<<<(SQ / 256) * (DIN / 256), 512, 0, stream>>>(ctx, wot, (float*)d_out, SQ, DIN, DIN);
}

// Round 6
// 591.174 us; speedup vs baseline: 1.0421x; 1.0122x over previous
//
#include <hip/hip_runtime.h>
#include <stdint.h>

#define SQ   2048
#define DIN  4096
#define NH   32
#define NKV  8
#define HD   128
#define NQKV 6144

typedef float f32x4 __attribute__((ext_vector_type(4)));
typedef short bf16x8 __attribute__((ext_vector_type(8)));

__device__ __forceinline__ short f2bf(float f) {
  union { float f; uint32_t u; } v; v.f = f;
  uint32_t r = (v.u + 0x7FFFu + ((v.u >> 16) & 1u)) >> 16;
  return (short)r;
}

// async global -> LDS, 16 bytes per lane, dst = lds_base + lane*16 (HW-fixed)
__device__ __forceinline__ void gl2lds(const void* g, void* l) {
  __builtin_amdgcn_global_load_lds(
      (const __attribute__((address_space(1))) void*)g,
      (__attribute__((address_space(3))) void*)l, 16, 0, 0);
}

// ---------------- fp32 -> bf16 elementwise convert ----------------
__global__ void cvt_bf16(const float* __restrict__ src, short* __restrict__ dst, long n) {
  long i = ((long)blockIdx.x * blockDim.x + threadIdx.x) * 4;
  if (i + 3 < n) {
    float4 v = *(const float4*)(src + i);
    short o[4] = { f2bf(v.x), f2bf(v.y), f2bf(v.z), f2bf(v.w) };
    *(uint2*)(dst + i) = *(uint2*)o;
  }
}

// ---------------- tiled transpose + convert: dst[c][r] = src[r][c] ----------------
__global__ __launch_bounds__(256) void transpose_cvt(const float* __restrict__ src, int ldS, long zS,
                                                     short* __restrict__ dst, int ldD, long zD) {
  __shared__ float tile[64][65];
  src += (long)blockIdx.z * zS;
  dst += (long)blockIdx.z * zD;
  int r0 = blockIdx.y * 64, c0 = blockIdx.x * 64;
  int tid = threadIdx.x;
#pragma unroll
  for (int i = 0; i < 16; ++i) {
    int idx = i * 256 + tid;
    int rr = idx >> 6, cc = idx & 63;
    tile[rr][cc] = src[(long)(r0 + rr) * ldS + c0 + cc];
  }
  __syncthreads();
#pragma unroll
  for (int i = 0; i < 16; ++i) {
    int idx = i * 256 + tid;
    int dr = idx >> 6, dc = idx & 63;
    dst[(long)(c0 + dr) * ldD + r0 + dc] = f2bf(tile[dc][dr]);
  }
}

// ---------------- 256x256 4-phase bf16 GEMM, conflict-free LDS ----------------
// (byte-identical to the round-3 kernel that benched 135 us/dispatch, 0 conflicts)
#define ASZ   16384   // shorts: A panel per buffer (256 rows x 64)
#define BUFSZ 32768   // shorts per buffer (A + B)
#define MFMA(d, a, b) d = __builtin_amdgcn_mfma_f32_16x16x32_bf16(a, b, d, 0, 0, 0)

#define SA(t) { short* d = &lds[(((t) & 1) * BUFSZ) + dA]; const short* s = aS + (long)(t) * 64; \
                gl2lds(s, d); gl2lds(s + K8, d + 512); gl2lds(s + 2 * K8, d + 1024); gl2lds(s + 3 * K8, d + 1536); }
#define SB(t) { short* d = &lds[(((t) & 1) * BUFSZ) + dB]; const short* s = bS + (long)(t) * 64; \
                gl2lds(s, d); gl2lds(s + K8, d + 512); gl2lds(s + 2 * K8, d + 1024); gl2lds(s + 3 * K8, d + 1536); }

__global__ __launch_bounds__(512, 2) void gemm8p(const short* __restrict__ A, const short* __restrict__ Bt,
                                                 float* __restrict__ C, int M, int N, int K) {
  __shared__ __align__(16) short lds[2 * BUFSZ];
  int nwg = gridDim.x;
  int lin = ((int)blockIdx.x & 7) * (nwg >> 3) + ((int)blockIdx.x >> 3);
  int mt = M >> 8;
  int m0 = (lin % mt) << 8, n0 = (lin / mt) << 8;

  int tid = threadIdx.x;
  int w = tid >> 6, lane = tid & 63;
  int l16 = lane & 15, lq = lane >> 4;
  int wm = (w >> 2) << 7;   // 0 / 128
  int wn = (w & 3) << 6;    // 0 / 64 / 128 / 192

  int s7 = l16 & 7;
  int fo0 = ((lq ^ s7) << 3);          // kk0
  int fo1 = (((lq + 4) ^ s7) << 3);    // kk1
  int arow = (wm + l16) * 64;          // + i*1024
  int brow = ASZ + (wn + l16) * 64;    // + j*1024

  int srow = lane >> 3;
  int gch = (lane & 7) ^ srow;
  const short* aS = A + (long)(m0 + 32 * w + srow) * K + gch * 8;
  const short* bS = Bt + (long)(n0 + 32 * w + srow) * K + gch * 8;
  long K8 = 8L * K;
  int dA = (32 * w) * 64;
  int dB = ASZ + (32 * w) * 64;

  f32x4 acc[8][4] = {};
  const int KT = K >> 6;

  SA(0); SB(0);
  asm volatile("s_waitcnt vmcnt(0)" ::: "memory");
  __builtin_amdgcn_s_barrier();

  for (int t = 0; t < KT; ++t) {
    const short* buf = &lds[(t & 1) * BUFSZ];
    bool s1 = (t + 1 < KT);
    bf16x8 af[8], b0, b1;

    // ---- phase 1: kk0 x j01 ; issue A(t+1) ----
#pragma unroll
    for (int i = 0; i < 8; ++i) af[i] = *(const bf16x8*)&buf[arow + i * 1024 + fo0];
    b0 = *(const bf16x8*)&buf[brow + fo0];
    b1 = *(const bf16x8*)&buf[brow + 1024 + fo0];
    if (s1) SA(t + 1);
    __builtin_amdgcn_s_barrier();
    asm volatile("s_waitcnt lgkmcnt(0)" ::: "memory");
    __builtin_amdgcn_s_setprio(1);
#pragma unroll
    for (int i = 0; i < 8; ++i) { MFMA(acc[i][0], af[i], b0); MFMA(acc[i][1], af[i], b1); }
    __builtin_amdgcn_s_setprio(0);
    __builtin_amdgcn_s_barrier();

    // ---- phase 2: kk0 x j23 ; issue B(t+1) ----
    b0 = *(const bf16x8*)&buf[brow + 2048 + fo0];
    b1 = *(const bf16x8*)&buf[brow + 3072 + fo0];
    if (s1) SB(t + 1);
    __builtin_amdgcn_s_barrier();
    asm volatile("s_waitcnt lgkmcnt(0)" ::: "memory");
    __builtin_amdgcn_s_setprio(1);
#pragma unroll
    for (int i = 0; i < 8; ++i) { MFMA(acc[i][2], af[i], b0); MFMA(acc[i][3], af[i], b1); }
    __builtin_amdgcn_s_setprio(0);
    __builtin_amdgcn_s_barrier();

    // ---- phase 3: kk1 x j23 ----
#pragma unroll
    for (int i = 0; i < 8; ++i) af[i] = *(const bf16x8*)&buf[arow + i * 1024 + fo1];
    b0 = *(const bf16x8*)&buf[brow + 2048 + fo1];
    b1 = *(const bf16x8*)&buf[brow + 3072 + fo1];
    __builtin_amdgcn_s_barrier();
    asm volatile("s_waitcnt lgkmcnt(0)" ::: "memory");
    __builtin_amdgcn_s_setprio(1);
#pragma unroll
    for (int i = 0; i < 8; ++i) { MFMA(acc[i][2], af[i], b0); MFMA(acc[i][3], af[i], b1); }
    __builtin_amdgcn_s_setprio(0);
    __builtin_amdgcn_s_barrier();

    // ---- phase 4: kk1 x j01 ; K-tile boundary ----
    b0 = *(const bf16x8*)&buf[brow + fo1];
    b1 = *(const bf16x8*)&buf[brow + 1024 + fo1];
    __builtin_amdgcn_s_barrier();
    asm volatile("s_waitcnt lgkmcnt(0)" ::: "memory");
    __builtin_amdgcn_s_setprio(1);
#pragma unroll
    for (int i = 0; i < 8; ++i) { MFMA(acc[i][0], af[i], b0); MFMA(acc[i][1], af[i], b1); }
    __builtin_amdgcn_s_setprio(0);
    if (s1) {
      asm volatile("s_waitcnt vmcnt(0)" ::: "memory");   // ~3-phase lead: no drain stall
      __builtin_amdgcn_s_barrier();
    }
  }

  // ---- epilogue: C-write (col=lane&15, row=(lane>>4)*4+reg) ----
#pragma unroll
  for (int i = 0; i < 8; ++i)
#pragma unroll
    for (int j = 0; j < 4; ++j)
#pragma unroll
      for (int r = 0; r < 4; ++r)
        C[(long)(m0 + wm + i * 16 + lq * 4 + r) * N + n0 + wn + j * 16 + l16] = acc[i][j][r];
}

// ---------------- fused LayerNorm + RoPE ----------------
__global__ __launch_bounds__(64) void ln_rope(const float* __restrict__ qkv,
                                              const float* __restrict__ cosb, const float* __restrict__ sinb,
                                              const float* __restrict__ qw, const float* __restrict__ qb,
                                              const float* __restrict__ kw, const float* __restrict__ kb,
                                              short* __restrict__ qo, short* __restrict__ ko) {
  int s = blockIdx.x, slice = blockIdx.y, t = threadIdx.x;
  bool isq = slice < NH;
  int off = isq ? slice * HD : DIN + (slice - NH) * HD;
  const float* src = qkv + (long)s * NQKV + off;
  float v0 = src[t], v1 = src[t + 64];
  float sum = v0 + v1, ss = v0 * v0 + v1 * v1;
#pragma unroll
  for (int o = 1; o < 64; o <<= 1) { sum += __shfl_xor(sum, o); ss += __shfl_xor(ss, o); }
  float mu = sum * (1.f / 128.f);
  float var = ss * (1.f / 128.f) - mu * mu;
  float rstd = rsqrtf(var + 1e-6f);
  const float* w  = isq ? qw : kw;
  const float* bb = isq ? qb : kb;
  float n0 = (v0 - mu) * rstd * w[t]      + bb[t];
  float n1 = (v1 - mu) * rstd * w[t + 64] + bb[t + 64];
  float c0 = cosb[s * HD + t], c1 = cosb[s * HD + t + 64];
  float s0 = sinb[s * HD + t], s1 = sinb[s * HD + t + 64];
  float o0 = n0 * c0 - n1 * s0;
  float o1 = n1 * c1 + n0 * s1;
  short* dst = isq ? (qo + ((long)slice * SQ + s) * HD)
                   : (ko + ((long)(slice - NH) * SQ + s) * HD);
  dst[t] = f2bf(o0);
  dst[t + 64] = f2bf(o1);
}

// ---------------- flash attention, double-buffered K/V, causal-paired ----------------
// grid (16 pairs, 32 heads), block 256 = 4 waves. Block p handles q-tiles p and 31-p.
// K tile 64x128 and V^T tile 128x64 DOUBLE-BUFFERED in LDS (2x32 KB): per key-tile,
// issue next tile's 8 gl2lds into buf^1, then s_waitcnt vmcnt(8) (current tile's
// loads are the older 8 -> prefetch stays in flight across the barrier; same
// counted-vmcnt pattern as the GEMM, HW-verified rounds 1-3).
// Softmax: defer-rescale (T13, THR=8 in exp2 domain) skips the acc*alpha pass +
// max update when the whole wave's row maxima grew by <= 8. Causal mask applied
// only on the diagonal tile (kt == qt); all earlier tiles are fully unmasked.
__global__ __launch_bounds__(256) void attn(const short* __restrict__ q, const short* __restrict__ k,
                                            const short* __restrict__ vT, short* __restrict__ ctx) {
  int pair = blockIdx.x, h = blockIdx.y, g = h >> 2;
  int tid = threadIdx.x, w = tid >> 6, lane = tid & 63;
  int l16 = lane & 15, lq = lane >> 4;
  __shared__ __align__(16) short Ks[2][64 * 128];   // [key][128], chunk16 ^ (key&15)
  __shared__ __align__(16) short Vs[2][128 * 64];   // [d][64],    chunk8  ^ (d&7)
  __shared__ __align__(16) short pbuf[4][16 * 72];
  const short* qh = q + (long)h * SQ * HD;
  const short* kg = k + (long)g * SQ * HD;
  const short* vg = vT + (long)g * HD * SQ;
  int kr = (w * 4) * 4 + (lane >> 4);             // K: call w*4+j covers rows (w*4+j)*4 + lane/16
  int vrw = (w * 4) * 8 + (lane >> 3);            // V: call w*4+j covers rows (w*4+j)*8 + lane/8
  const float sc = 0.08838834764831845f * 1.4426950408889634f;  // 1/sqrt(128) * log2(e)

  for (int st = 0; st < 2; ++st) {
    int qt = st ? (31 - pair) : pair;
    int qbase = qt * 64 + w * 16;
    bf16x8 aq[4];
#pragma unroll
    for (int kk = 0; kk < 4; ++kk)
      aq[kk] = *(const bf16x8*)&qh[(long)(qbase + l16) * HD + kk * 32 + lq * 8];
    float m_r[4], l_r[4];
    f32x4 acc[8] = {};
#pragma unroll
    for (int r = 0; r < 4; ++r) { m_r[r] = -__builtin_inff(); l_r[r] = 0.f; }

    // ---- prologue: stage tile 0 into buffer 0 ----
#pragma unroll
    for (int j = 0; j < 4; ++j) {
      int call = w * 4 + j;
      int r = kr + j * 4;
      int chk = (lane & 15) ^ (r & 15);
      gl2lds(&kg[(long)r * HD + chk * 8], &Ks[0][call * 512]);
      int rv = vrw + j * 8;
      int chv = (lane & 7) ^ (rv & 7);
      gl2lds(&vg[(long)rv * SQ + chv * 8], &Vs[0][call * 512]);
    }

    for (int kt = 0; kt <= qt; ++kt) {
      int cur = kt & 1;
      bool more = kt < qt;
      // ---- issue next tile's stage into buf^1, then counted wait on current ----
      if (more) {
#pragma unroll
        for (int j = 0; j < 4; ++j) {
          int call = w * 4 + j;
          int r = kr + j * 4;
          int chk = (lane & 15) ^ (r & 15);
          gl2lds(&kg[(long)((kt + 1) * 64 + r) * HD + chk * 8], &Ks[cur ^ 1][call * 512]);
          int rv = vrw + j * 8;
          int chv = (lane & 7) ^ (rv & 7);
          gl2lds(&vg[(long)rv * SQ + (kt + 1) * 64 + chv * 8], &Vs[cur ^ 1][call * 512]);
        }
        asm volatile("s_waitcnt vmcnt(8)" ::: "memory");  // current tile landed; prefetch in flight
      } else {
        asm volatile("s_waitcnt vmcnt(0)" ::: "memory");
      }
      __builtin_amdgcn_s_barrier();

      // ---- QK^T from Ks[cur] ----
      f32x4 s4[4];
#pragma unroll
      for (int b = 0; b < 4; ++b) s4[b] = (f32x4){0.f, 0.f, 0.f, 0.f};
#pragma unroll
      for (int b = 0; b < 4; ++b) {
        int krow = b * 16 + l16;
#pragma unroll
        for (int kk = 0; kk < 4; ++kk) {
          bf16x8 bk = *(const bf16x8*)&Ks[cur][krow * 128 + ((kk * 4 + lq) ^ (krow & 15)) * 8];
          s4[b] = __builtin_amdgcn_mfma_f32_16x16x32_bf16(aq[kk], bk, s4[b], 0, 0, 0);
        }
      }
      // ---- scale; causal mask only on the diagonal tile ----
      int qrow0 = qbase + lq * 4;
      if (kt == qt) {
#pragma unroll
        for (int b = 0; b < 4; ++b) {
          int key = kt * 64 + b * 16 + l16;
#pragma unroll
          for (int r = 0; r < 4; ++r) {
            float val = s4[b][r] * sc;
            s4[b][r] = (key > qrow0 + r) ? -__builtin_inff() : val;
          }
        }
      } else {
#pragma unroll
        for (int b = 0; b < 4; ++b)
#pragma unroll
          for (int r = 0; r < 4; ++r) s4[b][r] *= sc;
      }
      // ---- online softmax with defer-rescale (THR = 8 in exp2 domain) ----
      float mx4[4];
      bool defer = true;
#pragma unroll
      for (int r = 0; r < 4; ++r) {
        float mx = fmaxf(fmaxf(s4[0][r], s4[1][r]), fmaxf(s4[2][r], s4[3][r]));
#pragma unroll
        for (int o = 1; o < 16; o <<= 1) mx = fmaxf(mx, __shfl_xor(mx, o));
        mx4[r] = mx;
        defer = defer && (mx - m_r[r] <= 8.f);
      }
      if (!__all((int)defer)) {
#pragma unroll
        for (int r = 0; r < 4; ++r) {
          float mnew = fmaxf(m_r[r], mx4[r]);
          float alpha = exp2f(m_r[r] - mnew);
          l_r[r] *= alpha;
          m_r[r] = mnew;
#pragma unroll
          for (int n = 0; n < 8; ++n) acc[n][r] *= alpha;
        }
      }
      float p[4][4];
#pragma unroll
      for (int r = 0; r < 4; ++r) {
        float sum = 0.f;
#pragma unroll
        for (int b = 0; b < 4; ++b) { float pv = exp2f(s4[b][r] - m_r[r]); p[b][r] = pv; sum += pv; }
#pragma unroll
        for (int o = 1; o < 16; o <<= 1) sum += __shfl_xor(sum, o);
        l_r[r] += sum;
      }
      // ---- P (C-layout) -> LDS -> A-layout ----
#pragma unroll
      for (int b = 0; b < 4; ++b)
#pragma unroll
        for (int r = 0; r < 4; ++r)
          pbuf[w][(lq * 4 + r) * 72 + b * 16 + l16] = f2bf(p[b][r]);
      // ---- PV from Vs[cur] ----
#pragma unroll
      for (int kk = 0; kk < 2; ++kk) {
        bf16x8 pf = *(const bf16x8*)&pbuf[w][l16 * 72 + kk * 32 + lq * 8];
#pragma unroll
        for (int n = 0; n < 8; ++n) {
          int vrow = n * 16 + l16;
          bf16x8 vf = *(const bf16x8*)&Vs[cur][vrow * 64 + ((kk * 4 + lq) ^ (vrow & 7)) * 8];
          acc[n] = __builtin_amdgcn_mfma_f32_16x16x32_bf16(pf, vf, acc[n], 0, 0, 0);
        }
      }
      __builtin_amdgcn_s_barrier();   // all reads of buf[cur] done before next iter overwrites it
    }
    // ---- epilogue ----
#pragma unroll
    for (int n = 0; n < 8; ++n)
#pragma unroll
      for (int r = 0; r < 4; ++r) {
        int srow = qbase + lq * 4 + r;
        ctx[(long)srow * (NH * HD) + h * HD + n * 16 + l16] = f2bf(acc[n][r] / l_r[r]);
      }
  }
}

// ---------------- workspace layout ----------------
#define XB_OFF     0L
#define QR_OFF     0L
#define WQKVT_OFF  16777216L
#define KR_OFF     16777216L
#define VT_OFF     20971520L
#define CTX_OFF    25165824L
#define WOT_OFF    67108864L
#define QKV_OFF    100663296L

extern "C" void kernel_launch(void* const* d_in, const int* in_sizes, int n_in,
                              void* d_out, int out_size, void* d_ws, size_t ws_size,
                              hipStream_t stream) {
  const float* x    = (const float*)d_in[0];
  const float* cosb = (const float*)d_in[2];
  const float* sinb = (const float*)d_in[3];
  const float* Wq   = (const float*)d_in[4];
  const float* Wk   = (const float*)d_in[5];
  const float* Wv   = (const float*)d_in[6];
  const float* Wo   = (const float*)d_in[7];
  const float* qnw  = (const float*)d_in[8];
  const float* qnb  = (const float*)d_in[9];
  const float* knw  = (const float*)d_in[10];
  const float* knb  = (const float*)d_in[11];

  char* ws = (char*)d_ws;
  short* xb    = (short*)(ws + XB_OFF);
  short* qr    = (short*)(ws + QR_OFF);
  short* wqkvt = (short*)(ws + WQKVT_OFF);
  short* krp   = (short*)(ws + KR_OFF);
  short* vt    = (short*)(ws + VT_OFF);
  short* ctx   = (short*)(ws + CTX_OFF);
  short* wot   = (short*)(ws + WOT_OFF);
  float* qkv   = (float*)(ws + QKV_OFF);

  cvt_bf16<<<8192, 256, 0, stream>>>(x, xb, (long)SQ * DIN);
  transpose_cvt<<<dim3(64, 64, 1), 256, 0, stream>>>(Wq, 4096, 0L, wqkvt, 4096, 0L);
  transpose_cvt<<<dim3(16, 64, 1), 256, 0, stream>>>(Wk, 1024, 0L, wqkvt + (long)4096 * 4096, 4096, 0L);
  transpose_cvt<<<dim3(16, 64, 1), 256, 0, stream>>>(Wv, 1024, 0L, wqkvt + (long)5120 * 4096, 4096, 0L);
  transpose_cvt<<<dim3(64, 64, 1), 256, 0, stream>>>(Wo, 4096, 0L, wot, 4096, 0L);
  gemm8p<<<(SQ / 256) * (NQKV / 256), 512, 0, stream>>>(xb, wqkvt, qkv, SQ, NQKV, DIN);
  ln_rope<<<dim3(SQ, NH + NKV), 64, 0, stream>>>(qkv, cosb, sinb, qnw, qnb, knw, knb, qr, krp);
  transpose_cvt<<<dim3(2, 32, 8), 256, 0, stream>>>(qkv + 5120, NQKV, 128L, vt, SQ, (long)HD * SQ);
  attn<<<dim3(16, NH), 256, 0, stream>>>(qr, krp, vt, ctx);
  gemm8p<<<(SQ / 256) * (DIN / 256), 512, 0, stream>>>(ctx, wot, (float*)d_out, SQ, DIN, DIN);
}

// Round 7
// 546.826 us; speedup vs baseline: 1.1266x; 1.0811x over previous
//
#include <hip/hip_runtime.h>
#include <stdint.h>

#define SQ   2048
#define DIN  4096
#define NH   32
#define NKV  8
#define HD   128
#define NQKV 6144

typedef float f32x4 __attribute__((ext_vector_type(4)));
typedef short bf16x8 __attribute__((ext_vector_type(8)));

__device__ __forceinline__ short f2bf(float f) {
  union { float f; uint32_t u; } v; v.f = f;
  uint32_t r = (v.u + 0x7FFFu + ((v.u >> 16) & 1u)) >> 16;
  return (short)r;
}

// async global -> LDS, 16 bytes per lane, dst = lds_base + lane*16 (HW-fixed)
__device__ __forceinline__ void gl2lds(const void* g, void* l) {
  __builtin_amdgcn_global_load_lds(
      (const __attribute__((address_space(1))) void*)g,
      (__attribute__((address_space(3))) void*)l, 16, 0, 0);
}

// ---------------- fp32 -> bf16 elementwise convert ----------------
__global__ void cvt_bf16(const float* __restrict__ src, short* __restrict__ dst, long n) {
  long i = ((long)blockIdx.x * blockDim.x + threadIdx.x) * 4;
  if (i + 3 < n) {
    float4 v = *(const float4*)(src + i);
    short o[4] = { f2bf(v.x), f2bf(v.y), f2bf(v.z), f2bf(v.w) };
    *(uint2*)(dst + i) = *(uint2*)o;
  }
}

// ---------------- tiled transpose + convert: dst[c][r] = src[r][c] ----------------
__global__ __launch_bounds__(256) void transpose_cvt(const float* __restrict__ src, int ldS, long zS,
                                                     short* __restrict__ dst, int ldD, long zD) {
  __shared__ float tile[64][65];
  src += (long)blockIdx.z * zS;
  dst += (long)blockIdx.z * zD;
  int r0 = blockIdx.y * 64, c0 = blockIdx.x * 64;
  int tid = threadIdx.x;
#pragma unroll
  for (int i = 0; i < 16; ++i) {
    int idx = i * 256 + tid;
    int rr = idx >> 6, cc = idx & 63;
    tile[rr][cc] = src[(long)(r0 + rr) * ldS + c0 + cc];
  }
  __syncthreads();
#pragma unroll
  for (int i = 0; i < 16; ++i) {
    int idx = i * 256 + tid;
    int dr = idx >> 6, dc = idx & 63;
    dst[(long)(c0 + dr) * ldD + r0 + dc] = f2bf(tile[dc][dr]);
  }
}

// ---------------- 256x256 4-phase bf16 GEMM (round-3 baseline, sentinel) ----------------
#define ASZ   16384   // shorts: A panel per buffer (256 rows x 64)
#define BUFSZ 32768   // shorts per buffer (A + B)
#define MFMA(d, a, b) d = __builtin_amdgcn_mfma_f32_16x16x32_bf16(a, b, d, 0, 0, 0)

#define SA(t) { short* d = &lds[(((t) & 1) * BUFSZ) + dA]; const short* s = aS + (long)(t) * 64; \
                gl2lds(s, d); gl2lds(s + K8, d + 512); gl2lds(s + 2 * K8, d + 1024); gl2lds(s + 3 * K8, d + 1536); }
#define SB(t) { short* d = &lds[(((t) & 1) * BUFSZ) + dB]; const short* s = bS + (long)(t) * 64; \
                gl2lds(s, d); gl2lds(s + K8, d + 512); gl2lds(s + 2 * K8, d + 1024); gl2lds(s + 3 * K8, d + 1536); }

__global__ __launch_bounds__(512, 2) void gemm8p(const short* __restrict__ A, const short* __restrict__ Bt,
                                                 float* __restrict__ C, int M, int N, int K) {
  __shared__ __align__(16) short lds[2 * BUFSZ];
  int nwg = gridDim.x;
  int lin = ((int)blockIdx.x & 7) * (nwg >> 3) + ((int)blockIdx.x >> 3);
  int mt = M >> 8;
  int m0 = (lin % mt) << 8, n0 = (lin / mt) << 8;

  int tid = threadIdx.x;
  int w = tid >> 6, lane = tid & 63;
  int l16 = lane & 15, lq = lane >> 4;
  int wm = (w >> 2) << 7;   // 0 / 128
  int wn = (w & 3) << 6;    // 0 / 64 / 128 / 192

  int s7 = l16 & 7;
  int fo0 = ((lq ^ s7) << 3);          // kk0
  int fo1 = (((lq + 4) ^ s7) << 3);    // kk1
  int arow = (wm + l16) * 64;          // + i*1024
  int brow = ASZ + (wn + l16) * 64;    // + j*1024

  int srow = lane >> 3;
  int gch = (lane & 7) ^ srow;
  const short* aS = A + (long)(m0 + 32 * w + srow) * K + gch * 8;
  const short* bS = Bt + (long)(n0 + 32 * w + srow) * K + gch * 8;
  long K8 = 8L * K;
  int dA = (32 * w) * 64;
  int dB = ASZ + (32 * w) * 64;

  f32x4 acc[8][4] = {};
  const int KT = K >> 6;

  SA(0); SB(0);
  asm volatile("s_waitcnt vmcnt(0)" ::: "memory");
  __builtin_amdgcn_s_barrier();

  for (int t = 0; t < KT; ++t) {
    const short* buf = &lds[(t & 1) * BUFSZ];
    bool s1 = (t + 1 < KT);
    bf16x8 af[8], b0, b1;

    // ---- phase 1: kk0 x j01 ; issue A(t+1) ----
#pragma unroll
    for (int i = 0; i < 8; ++i) af[i] = *(const bf16x8*)&buf[arow + i * 1024 + fo0];
    b0 = *(const bf16x8*)&buf[brow + fo0];
    b1 = *(const bf16x8*)&buf[brow + 1024 + fo0];
    if (s1) SA(t + 1);
    __builtin_amdgcn_s_barrier();
    asm volatile("s_waitcnt lgkmcnt(0)" ::: "memory");
    __builtin_amdgcn_s_setprio(1);
#pragma unroll
    for (int i = 0; i < 8; ++i) { MFMA(acc[i][0], af[i], b0); MFMA(acc[i][1], af[i], b1); }
    __builtin_amdgcn_s_setprio(0);
    __builtin_amdgcn_s_barrier();

    // ---- phase 2: kk0 x j23 ; issue B(t+1) ----
    b0 = *(const bf16x8*)&buf[brow + 2048 + fo0];
    b1 = *(const bf16x8*)&buf[brow + 3072 + fo0];
    if (s1) SB(t + 1);
    __builtin_amdgcn_s_barrier();
    asm volatile("s_waitcnt lgkmcnt(0)" ::: "memory");
    __builtin_amdgcn_s_setprio(1);
#pragma unroll
    for (int i = 0; i < 8; ++i) { MFMA(acc[i][2], af[i], b0); MFMA(acc[i][3], af[i], b1); }
    __builtin_amdgcn_s_setprio(0);
    __builtin_amdgcn_s_barrier();

    // ---- phase 3: kk1 x j23 ----
#pragma unroll
    for (int i = 0; i < 8; ++i) af[i] = *(const bf16x8*)&buf[arow + i * 1024 + fo1];
    b0 = *(const bf16x8*)&buf[brow + 2048 + fo1];
    b1 = *(const bf16x8*)&buf[brow + 3072 + fo1];
    __builtin_amdgcn_s_barrier();
    asm volatile("s_waitcnt lgkmcnt(0)" ::: "memory");
    __builtin_amdgcn_s_setprio(1);
#pragma unroll
    for (int i = 0; i < 8; ++i) { MFMA(acc[i][2], af[i], b0); MFMA(acc[i][3], af[i], b1); }
    __builtin_amdgcn_s_setprio(0);
    __builtin_amdgcn_s_barrier();

    // ---- phase 4: kk1 x j01 ; K-tile boundary ----
    b0 = *(const bf16x8*)&buf[brow + fo1];
    b1 = *(const bf16x8*)&buf[brow + 1024 + fo1];
    __builtin_amdgcn_s_barrier();
    asm volatile("s_waitcnt lgkmcnt(0)" ::: "memory");
    __builtin_amdgcn_s_setprio(1);
#pragma unroll
    for (int i = 0; i < 8; ++i) { MFMA(acc[i][0], af[i], b0); MFMA(acc[i][1], af[i], b1); }
    __builtin_amdgcn_s_setprio(0);
    if (s1) {
      asm volatile("s_waitcnt vmcnt(0)" ::: "memory");
      __builtin_amdgcn_s_barrier();
    }
  }

#pragma unroll
  for (int i = 0; i < 8; ++i)
#pragma unroll
    for (int j = 0; j < 4; ++j)
#pragma unroll
      for (int r = 0; r < 4; ++r)
        C[(long)(m0 + wm + i * 16 + lq * 4 + r) * N + n0 + wn + j * 16 + l16] = acc[i][j][r];
}

// ---------------- 256x128 bf16 GEMM, 3-buffer counted-vmcnt pipeline ----------------
// BM=256, BN=128, BK=64, 512 thr = 8 waves (4M x 2N), per-wave 64x64 (acc[4][4]).
// 2 phases/tile of 16 MFMA. THREE LDS buffers (3 x 48 KB = 144 KB): compute t from
// buf(t%3) while staging t+2 into buf((t+2)%3) (SA3 4 loads in ph1, SB3 2 in ph2).
// Tile boundary waits vmcnt(6): t+1's 6 loads (issued a full tile ago) drained,
// t+2's 6 stay in flight -- vmcnt never drains to 0 in steady state (T4).
// Race: buf((t+2)%3)'s last reads were tile t-1's, consumed before t-1's boundary
// barrier, which precedes t's staging issue. LDS layout as gemm8p (conflict-free).
#define A3SZ 16384   // shorts: A panel (256 x 64)
#define T3SZ 24576   // shorts per buffer (A 32KB + B 16KB)

#define SA3(t) { short* d = &lds[((t) % 3) * T3SZ + dA]; const short* s = aS + (long)(t) * 64; \
                 gl2lds(s, d); gl2lds(s + K8, d + 512); gl2lds(s + 2 * K8, d + 1024); gl2lds(s + 3 * K8, d + 1536); }
#define SB3(t) { short* d = &lds[((t) % 3) * T3SZ + dB]; const short* s = bS + (long)(t) * 64; \
                 gl2lds(s, d); gl2lds(s + K8, d + 512); }

__global__ __launch_bounds__(512) void gemm3b(const short* __restrict__ A, const short* __restrict__ Bt,
                                              float* __restrict__ C, int M, int N, int K) {
  __shared__ __align__(16) short lds[3 * T3SZ];
  int nwg = gridDim.x;
  int lin = ((int)blockIdx.x & 7) * (nwg >> 3) + ((int)blockIdx.x >> 3);
  int mt = M >> 8;
  int m0 = (lin % mt) << 8, n0 = (lin / mt) << 7;

  int tid = threadIdx.x;
  int w = tid >> 6, lane = tid & 63;
  int l16 = lane & 15, lq = lane >> 4;
  int wm = (w >> 1) << 6;   // 0/64/128/192
  int wn = (w & 1) << 6;    // 0/64

  int s7 = l16 & 7;
  int fo0 = ((lq ^ s7) << 3);
  int fo1 = (((lq + 4) ^ s7) << 3);
  int arow = (wm + l16) * 64;           // + i*1024
  int brow = A3SZ + (wn + l16) * 64;    // + j*1024

  // staging: A rows 32w..32w+31 (4 calls), B rows 16w..16w+15 (2 calls)
  int srow = lane >> 3;
  int gch = (lane & 7) ^ srow;
  const short* aS = A + (long)(m0 + 32 * w + srow) * K + gch * 8;
  const short* bS = Bt + (long)(n0 + 16 * w + srow) * K + gch * 8;
  long K8 = 8L * K;
  int dA = w * 2048;            // 32w rows * 64 shorts
  int dB = A3SZ + w * 1024;     // 16w rows * 64 shorts

  f32x4 acc[4][4] = {};
  const int KT = K >> 6;

  // ---- prologue: stage tiles 0 and 1 (12 loads/thread) ----
  SA3(0); SB3(0); SA3(1); SB3(1);
  asm volatile("s_waitcnt vmcnt(6)" ::: "memory");   // tile 0 landed; tile 1 in flight
  __builtin_amdgcn_s_barrier();

  for (int t = 0; t < KT; ++t) {
    const short* buf = &lds[(t % 3) * T3SZ];
    bool s2 = (t + 2 < KT);
    bf16x8 af[4], bfv[4];

    // ---- phase 1 (kk0): 8 reads ; stage A(t+2) ; 16 MFMA ----
#pragma unroll
    for (int i = 0; i < 4; ++i) af[i] = *(const bf16x8*)&buf[arow + i * 1024 + fo0];
#pragma unroll
    for (int j = 0; j < 4; ++j) bfv[j] = *(const bf16x8*)&buf[brow + j * 1024 + fo0];
    if (s2) SA3(t + 2);
    __builtin_amdgcn_s_barrier();
    asm volatile("s_waitcnt lgkmcnt(0)" ::: "memory");
    __builtin_amdgcn_s_setprio(1);
#pragma unroll
    for (int i = 0; i < 4; ++i)
#pragma unroll
      for (int j = 0; j < 4; ++j) MFMA(acc[i][j], af[i], bfv[j]);
    __builtin_amdgcn_s_setprio(0);
    __builtin_amdgcn_s_barrier();

    // ---- phase 2 (kk1): 8 reads ; stage B(t+2) ; 16 MFMA ; boundary vmcnt(6) ----
#pragma unroll
    for (int i = 0; i < 4; ++i) af[i] = *(const bf16x8*)&buf[arow + i * 1024 + fo1];
#pragma unroll
    for (int j = 0; j < 4; ++j) bfv[j] = *(const bf16x8*)&buf[brow + j * 1024 + fo1];
    if (s2) SB3(t + 2);
    __builtin_amdgcn_s_barrier();
    asm volatile("s_waitcnt lgkmcnt(0)" ::: "memory");
    __builtin_amdgcn_s_setprio(1);
#pragma unroll
    for (int i = 0; i < 4; ++i)
#pragma unroll
      for (int j = 0; j < 4; ++j) MFMA(acc[i][j], af[i], bfv[j]);
    __builtin_amdgcn_s_setprio(0);
    if (t + 1 < KT) {
      if (s2) asm volatile("s_waitcnt vmcnt(6)" ::: "memory");   // t+1 landed; t+2 in flight
      else    asm volatile("s_waitcnt vmcnt(0)" ::: "memory");   // last boundary: drain
      __builtin_amdgcn_s_barrier();
    }
  }

  // ---- epilogue: C-write (col=lane&15, row=(lane>>4)*4+reg) ----
#pragma unroll
  for (int i = 0; i < 4; ++i)
#pragma unroll
    for (int j = 0; j < 4; ++j)
#pragma unroll
      for (int r = 0; r < 4; ++r)
        C[(long)(m0 + wm + i * 16 + lq * 4 + r) * N + n0 + wn + j * 16 + l16] = acc[i][j][r];
}

// ---------------- fused LayerNorm + RoPE ----------------
__global__ __launch_bounds__(64) void ln_rope(const float* __restrict__ qkv,
                                              const float* __restrict__ cosb, const float* __restrict__ sinb,
                                              const float* __restrict__ qw, const float* __restrict__ qb,
                                              const float* __restrict__ kw, const float* __restrict__ kb,
                                              short* __restrict__ qo, short* __restrict__ ko) {
  int s = blockIdx.x, slice = blockIdx.y, t = threadIdx.x;
  bool isq = slice < NH;
  int off = isq ? slice * HD : DIN + (slice - NH) * HD;
  const float* src = qkv + (long)s * NQKV + off;
  float v0 = src[t], v1 = src[t + 64];
  float sum = v0 + v1, ss = v0 * v0 + v1 * v1;
#pragma unroll
  for (int o = 1; o < 64; o <<= 1) { sum += __shfl_xor(sum, o); ss += __shfl_xor(ss, o); }
  float mu = sum * (1.f / 128.f);
  float var = ss * (1.f / 128.f) - mu * mu;
  float rstd = rsqrtf(var + 1e-6f);
  const float* w  = isq ? qw : kw;
  const float* bb = isq ? qb : kb;
  float n0 = (v0 - mu) * rstd * w[t]      + bb[t];
  float n1 = (v1 - mu) * rstd * w[t + 64] + bb[t + 64];
  float c0 = cosb[s * HD + t], c1 = cosb[s * HD + t + 64];
  float s0 = sinb[s * HD + t], s1 = sinb[s * HD + t + 64];
  float o0 = n0 * c0 - n1 * s0;
  float o1 = n1 * c1 + n0 * s1;
  short* dst = isq ? (qo + ((long)slice * SQ + s) * HD)
                   : (ko + ((long)(slice - NH) * SQ + s) * HD);
  dst[t] = f2bf(o0);
  dst[t + 64] = f2bf(o1);
}

// ---------------- flash attention, double-buffered K/V, causal-paired ----------------
__global__ __launch_bounds__(256) void attn(const short* __restrict__ q, const short* __restrict__ k,
                                            const short* __restrict__ vT, short* __restrict__ ctx) {
  int pair = blockIdx.x, h = blockIdx.y, g = h >> 2;
  int tid = threadIdx.x, w = tid >> 6, lane = tid & 63;
  int l16 = lane & 15, lq = lane >> 4;
  __shared__ __align__(16) short Ks[2][64 * 128];   // [key][128], chunk16 ^ (key&15)
  __shared__ __align__(16) short Vs[2][128 * 64];   // [d][64],    chunk8  ^ (d&7)
  __shared__ __align__(16) short pbuf[4][16 * 72];
  const short* qh = q + (long)h * SQ * HD;
  const short* kg = k + (long)g * SQ * HD;
  const short* vg = vT + (long)g * HD * SQ;
  int kr = (w * 4) * 4 + (lane >> 4);
  int vrw = (w * 4) * 8 + (lane >> 3);
  const float sc = 0.08838834764831845f * 1.4426950408889634f;  // 1/sqrt(128) * log2(e)

  for (int st = 0; st < 2; ++st) {
    int qt = st ? (31 - pair) : pair;
    int qbase = qt * 64 + w * 16;
    bf16x8 aq[4];
#pragma unroll
    for (int kk = 0; kk < 4; ++kk)
      aq[kk] = *(const bf16x8*)&qh[(long)(qbase + l16) * HD + kk * 32 + lq * 8];
    float m_r[4], l_r[4];
    f32x4 acc[8] = {};
#pragma unroll
    for (int r = 0; r < 4; ++r) { m_r[r] = -__builtin_inff(); l_r[r] = 0.f; }

#pragma unroll
    for (int j = 0; j < 4; ++j) {
      int call = w * 4 + j;
      int r = kr + j * 4;
      int chk = (lane & 15) ^ (r & 15);
      gl2lds(&kg[(long)r * HD + chk * 8], &Ks[0][call * 512]);
      int rv = vrw + j * 8;
      int chv = (lane & 7) ^ (rv & 7);
      gl2lds(&vg[(long)rv * SQ + chv * 8], &Vs[0][call * 512]);
    }

    for (int kt = 0; kt <= qt; ++kt) {
      int cur = kt & 1;
      bool more = kt < qt;
      if (more) {
#pragma unroll
        for (int j = 0; j < 4; ++j) {
          int call = w * 4 + j;
          int r = kr + j * 4;
          int chk = (lane & 15) ^ (r & 15);
          gl2lds(&kg[(long)((kt + 1) * 64 + r) * HD + chk * 8], &Ks[cur ^ 1][call * 512]);
          int rv = vrw + j * 8;
          int chv = (lane & 7) ^ (rv & 7);
          gl2lds(&vg[(long)rv * SQ + (kt + 1) * 64 + chv * 8], &Vs[cur ^ 1][call * 512]);
        }
        asm volatile("s_waitcnt vmcnt(8)" ::: "memory");
      } else {
        asm volatile("s_waitcnt vmcnt(0)" ::: "memory");
      }
      __builtin_amdgcn_s_barrier();

      f32x4 s4[4];
#pragma unroll
      for (int b = 0; b < 4; ++b) s4[b] = (f32x4){0.f, 0.f, 0.f, 0.f};
#pragma unroll
      for (int b = 0; b < 4; ++b) {
        int krow = b * 16 + l16;
#pragma unroll
        for (int kk = 0; kk < 4; ++kk) {
          bf16x8 bk = *(const bf16x8*)&Ks[cur][krow * 128 + ((kk * 4 + lq) ^ (krow & 15)) * 8];
          s4[b] = __builtin_amdgcn_mfma_f32_16x16x32_bf16(aq[kk], bk, s4[b], 0, 0, 0);
        }
      }
      int qrow0 = qbase + lq * 4;
      if (kt == qt) {
#pragma unroll
        for (int b = 0; b < 4; ++b) {
          int key = kt * 64 + b * 16 + l16;
#pragma unroll
          for (int r = 0; r < 4; ++r) {
            float val = s4[b][r] * sc;
            s4[b][r] = (key > qrow0 + r) ? -__builtin_inff() : val;
          }
        }
      } else {
#pragma unroll
        for (int b = 0; b < 4; ++b)
#pragma unroll
          for (int r = 0; r < 4; ++r) s4[b][r] *= sc;
      }
      float mx4[4];
      bool defer = true;
#pragma unroll
      for (int r = 0; r < 4; ++r) {
        float mx = fmaxf(fmaxf(s4[0][r], s4[1][r]), fmaxf(s4[2][r], s4[3][r]));
#pragma unroll
        for (int o = 1; o < 16; o <<= 1) mx = fmaxf(mx, __shfl_xor(mx, o));
        mx4[r] = mx;
        defer = defer && (mx - m_r[r] <= 8.f);
      }
      if (!__all((int)defer)) {
#pragma unroll
        for (int r = 0; r < 4; ++r) {
          float mnew = fmaxf(m_r[r], mx4[r]);
          float alpha = exp2f(m_r[r] - mnew);
          l_r[r] *= alpha;
          m_r[r] = mnew;
#pragma unroll
          for (int n = 0; n < 8; ++n) acc[n][r] *= alpha;
        }
      }
      float p[4][4];
#pragma unroll
      for (int r = 0; r < 4; ++r) {
        float sum = 0.f;
#pragma unroll
        for (int b = 0; b < 4; ++b) { float pv = exp2f(s4[b][r] - m_r[r]); p[b][r] = pv; sum += pv; }
#pragma unroll
        for (int o = 1; o < 16; o <<= 1) sum += __shfl_xor(sum, o);
        l_r[r] += sum;
      }
#pragma unroll
      for (int b = 0; b < 4; ++b)
#pragma unroll
        for (int r = 0; r < 4; ++r)
          pbuf[w][(lq * 4 + r) * 72 + b * 16 + l16] = f2bf(p[b][r]);
#pragma unroll
      for (int kk = 0; kk < 2; ++kk) {
        bf16x8 pf = *(const bf16x8*)&pbuf[w][l16 * 72 + kk * 32 + lq * 8];
#pragma unroll
        for (int n = 0; n < 8; ++n) {
          int vrow = n * 16 + l16;
          bf16x8 vf = *(const bf16x8*)&Vs[cur][vrow * 64 + ((kk * 4 + lq) ^ (vrow & 7)) * 8];
          acc[n] = __builtin_amdgcn_mfma_f32_16x16x32_bf16(pf, vf, acc[n], 0, 0, 0);
        }
      }
      __builtin_amdgcn_s_barrier();
    }
#pragma unroll
    for (int n = 0; n < 8; ++n)
#pragma unroll
      for (int r = 0; r < 4; ++r) {
        int srow = qbase + lq * 4 + r;
        ctx[(long)srow * (NH * HD) + h * HD + n * 16 + l16] = f2bf(acc[n][r] / l_r[r]);
      }
  }
}

// ---------------- workspace layout ----------------
#define XB_OFF     0L
#define QR_OFF     0L
#define WQKVT_OFF  16777216L
#define KR_OFF     16777216L
#define VT_OFF     20971520L
#define CTX_OFF    25165824L
#define WOT_OFF    67108864L
#define QKV_OFF    100663296L

extern "C" void kernel_launch(void* const* d_in, const int* in_sizes, int n_in,
                              void* d_out, int out_size, void* d_ws, size_t ws_size,
                              hipStream_t stream) {
  const float* x    = (const float*)d_in[0];
  const float* cosb = (const float*)d_in[2];
  const float* sinb = (const float*)d_in[3];
  const float* Wq   = (const float*)d_in[4];
  const float* Wk   = (const float*)d_in[5];
  const float* Wv   = (const float*)d_in[6];
  const float* Wo   = (const float*)d_in[7];
  const float* qnw  = (const float*)d_in[8];
  const float* qnb  = (const float*)d_in[9];
  const float* knw  = (const float*)d_in[10];
  const float* knb  = (const float*)d_in[11];

  char* ws = (char*)d_ws;
  short* xb    = (short*)(ws + XB_OFF);
  short* qr    = (short*)(ws + QR_OFF);
  short* wqkvt = (short*)(ws + WQKVT_OFF);
  short* krp   = (short*)(ws + KR_OFF);
  short* vt    = (short*)(ws + VT_OFF);
  short* ctx   = (short*)(ws + CTX_OFF);
  short* wot   = (short*)(ws + WOT_OFF);
  float* qkv   = (float*)(ws + QKV_OFF);

  cvt_bf16<<<8192, 256, 0, stream>>>(x, xb, (long)SQ * DIN);
  transpose_cvt<<<dim3(64, 64, 1), 256, 0, stream>>>(Wq, 4096, 0L, wqkvt, 4096, 0L);
  transpose_cvt<<<dim3(16, 64, 1), 256, 0, stream>>>(Wk, 1024, 0L, wqkvt + (long)4096 * 4096, 4096, 0L);
  transpose_cvt<<<dim3(16, 64, 1), 256, 0, stream>>>(Wv, 1024, 0L, wqkvt + (long)5120 * 4096, 4096, 0L);
  transpose_cvt<<<dim3(64, 64, 1), 256, 0, stream>>>(Wo, 4096, 0L, wot, 4096, 0L);
  gemm8p<<<(SQ / 256) * (NQKV / 256), 512, 0, stream>>>(xb, wqkvt, qkv, SQ, NQKV, DIN);
  ln_rope<<<dim3(SQ, NH + NKV), 64, 0, stream>>>(qkv, cosb, sinb, qnw, qnb, knw, knb, qr, krp);
  transpose_cvt<<<dim3(2, 32, 8), 256, 0, stream>>>(qkv + 5120, NQKV, 128L, vt, SQ, (long)HD * SQ);
  attn<<<dim3(16, NH), 256, 0, stream>>>(qr, krp, vt, ctx);
  gemm3b<<<(SQ / 256) * (DIN / 128), 512, 0, stream>>>(ctx, wot, (float*)d_out, SQ, DIN, DIN);
}

// Round 8
// 540.094 us; speedup vs baseline: 1.1406x; 1.0125x over previous
//
#include <hip/hip_runtime.h>
#include <stdint.h>

#define SQ   2048
#define DIN  4096
#define NH   32
#define NKV  8
#define HD   128
#define NQKV 6144

typedef float f32x4 __attribute__((ext_vector_type(4)));
typedef short bf16x8 __attribute__((ext_vector_type(8)));

__device__ __forceinline__ short f2bf(float f) {
  union { float f; uint32_t u; } v; v.f = f;
  uint32_t r = (v.u + 0x7FFFu + ((v.u >> 16) & 1u)) >> 16;
  return (short)r;
}

// async global -> LDS, 16 bytes per lane, dst = lds_base + lane*16 (HW-fixed)
__device__ __forceinline__ void gl2lds(const void* g, void* l) {
  __builtin_amdgcn_global_load_lds(
      (const __attribute__((address_space(1))) void*)g,
      (__attribute__((address_space(3))) void*)l, 16, 0, 0);
}

// ---------------- fp32 -> bf16 elementwise convert ----------------
__global__ void cvt_bf16(const float* __restrict__ src, short* __restrict__ dst, long n) {
  long i = ((long)blockIdx.x * blockDim.x + threadIdx.x) * 4;
  if (i + 3 < n) {
    float4 v = *(const float4*)(src + i);
    short o[4] = { f2bf(v.x), f2bf(v.y), f2bf(v.z), f2bf(v.w) };
    *(uint2*)(dst + i) = *(uint2*)o;
  }
}

// ---------------- tiled transpose + convert: dst[c][r] = src[r][c] ----------------
__global__ __launch_bounds__(256) void transpose_cvt(const float* __restrict__ src, int ldS, long zS,
                                                     short* __restrict__ dst, int ldD, long zD) {
  __shared__ float tile[64][65];
  src += (long)blockIdx.z * zS;
  dst += (long)blockIdx.z * zD;
  int r0 = blockIdx.y * 64, c0 = blockIdx.x * 64;
  int tid = threadIdx.x;
#pragma unroll
  for (int i = 0; i < 16; ++i) {
    int idx = i * 256 + tid;
    int rr = idx >> 6, cc = idx & 63;
    tile[rr][cc] = src[(long)(r0 + rr) * ldS + c0 + cc];
  }
  __syncthreads();
#pragma unroll
  for (int i = 0; i < 16; ++i) {
    int idx = i * 256 + tid;
    int dr = idx >> 6, dc = idx & 63;
    dst[(long)(c0 + dr) * ldD + r0 + dc] = f2bf(tile[dc][dr]);
  }
}

// ---------------- 256x256 bf16 GEMM, read-ahead pipelined ----------------
// BM=BN=256, BK=64, 512 thr = 8 waves (2M x 4N), per-wave 128x64.
// 4 segs/K-tile, ONE barrier per seg. Each seg issues the NEXT seg's fragment
// ds_reads, then MFMAs on fragments read LAST seg -> LDS returns stream under
// the MFMA cluster (round-7 counters: serialized read/MFMA windows = 5060
// cyc/tile vs 2480 MFMA floor; this overlaps the 1536-cyc LDS service).
//   seg1: read B-kk0-j23 ; stage A(t+1) ; MFMA a0 x P(kk0 j01)
//   seg2: read A-kk1 + B-kk1-j23 ; stage B(t+1) ; MFMA a0 x Q(kk0 j23)
//   seg3: read B-kk1-j01 ; MFMA a1 x P(kk1 j23) ; vmcnt(0) ; barrier(boundary)
//   seg4: read next-tile A-kk0 + B-kk0-j01 from fresh buffer ; MFMA a1 x Q
// Race audit: staging of t+1 (segs1-2 of t) writes the buffer whose last reads
// issued in seg3 of t-1 and were consumed (per-wave lgkm wait before MFMA use)
// before t-1's seg4-end barrier, which precedes t's staging issue. nbuf reads
// in seg4 gated by own-vmcnt(0)+barrier. All barriers uniform.
// LDS layout (verified 0 conflicts): rows = full BK=64 bf16 (128 B), slot =
// chunk^(row&7); gl2lds dst linear, global source chunk inverse-swizzled.
#define ASZ   16384   // shorts: A panel per buffer (256 rows x 64)
#define BUFSZ 32768   // shorts per buffer (A + B)
#define MFMA(d, a, b) d = __builtin_amdgcn_mfma_f32_16x16x32_bf16(a, b, d, 0, 0, 0)

#define SA(t) { short* d = &lds[(((t) & 1) * BUFSZ) + dA]; const short* s = aS + (long)(t) * 64; \
                gl2lds(s, d); gl2lds(s + K8, d + 512); gl2lds(s + 2 * K8, d + 1024); gl2lds(s + 3 * K8, d + 1536); }
#define SB(t) { short* d = &lds[(((t) & 1) * BUFSZ) + dB]; const short* s = bS + (long)(t) * 64; \
                gl2lds(s, d); gl2lds(s + K8, d + 512); gl2lds(s + 2 * K8, d + 1024); gl2lds(s + 3 * K8, d + 1536); }

__global__ __launch_bounds__(512, 2) void gemm8p(const short* __restrict__ A, const short* __restrict__ Bt,
                                                 float* __restrict__ C, int M, int N, int K) {
  __shared__ __align__(16) short lds[2 * BUFSZ];
  int nwg = gridDim.x;
  int lin = ((int)blockIdx.x & 7) * (nwg >> 3) + ((int)blockIdx.x >> 3);
  int mt = M >> 8;
  int m0 = (lin % mt) << 8, n0 = (lin / mt) << 8;

  int tid = threadIdx.x;
  int w = tid >> 6, lane = tid & 63;
  int l16 = lane & 15, lq = lane >> 4;
  int wm = (w >> 2) << 7;   // 0 / 128
  int wn = (w & 3) << 6;    // 0 / 64 / 128 / 192

  int s7 = l16 & 7;
  int fo0 = ((lq ^ s7) << 3);          // kk0
  int fo1 = (((lq + 4) ^ s7) << 3);    // kk1
  int arow = (wm + l16) * 64;          // + i*1024
  int brow = ASZ + (wn + l16) * 64;    // + j*1024

  int srow = lane >> 3;
  int gch = (lane & 7) ^ srow;
  const short* aS = A + (long)(m0 + 32 * w + srow) * K + gch * 8;
  const short* bS = Bt + (long)(n0 + 32 * w + srow) * K + gch * 8;
  long K8 = 8L * K;
  int dA = (32 * w) * 64;
  int dB = ASZ + (32 * w) * 64;

  f32x4 acc[8][4] = {};
  bf16x8 a0[8], a1[8], P0, P1, Q0, Q1;
  const int KT = K >> 6;

  // ---- prologue: stage tile 0, then preload seg1 fragments ----
  SA(0); SB(0);
  asm volatile("s_waitcnt vmcnt(0)" ::: "memory");
  __builtin_amdgcn_s_barrier();
  {
    const short* buf = &lds[0];
#pragma unroll
    for (int i = 0; i < 8; ++i) a0[i] = *(const bf16x8*)&buf[arow + i * 1024 + fo0];
    P0 = *(const bf16x8*)&buf[brow + fo0];
    P1 = *(const bf16x8*)&buf[brow + 1024 + fo0];
  }

  for (int t = 0; t < KT; ++t) {
    const short* buf  = &lds[(t & 1) * BUFSZ];
    const short* nbuf = &lds[((t + 1) & 1) * BUFSZ];
    bool s1 = (t + 1 < KT);

    // ---- seg1: read kk0-j23 ; stage A(t+1) ; MFMA a0 x kk0-j01 ----
    Q0 = *(const bf16x8*)&buf[brow + 2048 + fo0];
    Q1 = *(const bf16x8*)&buf[brow + 3072 + fo0];
    if (s1) SA(t + 1);
    __builtin_amdgcn_sched_barrier(0);
    __builtin_amdgcn_s_setprio(1);
#pragma unroll
    for (int i = 0; i < 8; ++i) { MFMA(acc[i][0], a0[i], P0); MFMA(acc[i][1], a0[i], P1); }
    __builtin_amdgcn_s_setprio(0);
    __builtin_amdgcn_s_barrier();

    // ---- seg2: read A-kk1 + kk1-j23 ; stage B(t+1) ; MFMA a0 x kk0-j23 ----
#pragma unroll
    for (int i = 0; i < 8; ++i) a1[i] = *(const bf16x8*)&buf[arow + i * 1024 + fo1];
    P0 = *(const bf16x8*)&buf[brow + 2048 + fo1];
    P1 = *(const bf16x8*)&buf[brow + 3072 + fo1];
    if (s1) SB(t + 1);
    __builtin_amdgcn_sched_barrier(0);
    __builtin_amdgcn_s_setprio(1);
#pragma unroll
    for (int i = 0; i < 8; ++i) { MFMA(acc[i][2], a0[i], Q0); MFMA(acc[i][3], a0[i], Q1); }
    __builtin_amdgcn_s_setprio(0);
    __builtin_amdgcn_s_barrier();

    // ---- seg3: read kk1-j01 ; MFMA a1 x kk1-j23 ; boundary vmcnt+barrier ----
    Q0 = *(const bf16x8*)&buf[brow + fo1];
    Q1 = *(const bf16x8*)&buf[brow + 1024 + fo1];
    __builtin_amdgcn_sched_barrier(0);
    __builtin_amdgcn_s_setprio(1);
#pragma unroll
    for (int i = 0; i < 8; ++i) { MFMA(acc[i][2], a1[i], P0); MFMA(acc[i][3], a1[i], P1); }
    __builtin_amdgcn_s_setprio(0);
    if (s1) asm volatile("s_waitcnt vmcnt(0)" ::: "memory");  // own staging of t+1 landed (~2-seg lead)
    __builtin_amdgcn_s_barrier();                             // boundary: buf(t+1) visible to all

    // ---- seg4: read next tile's kk0 set from fresh buffer ; MFMA a1 x kk1-j01 ----
    if (s1) {
#pragma unroll
      for (int i = 0; i < 8; ++i) a0[i] = *(const bf16x8*)&nbuf[arow + i * 1024 + fo0];
      P0 = *(const bf16x8*)&nbuf[brow + fo0];
      P1 = *(const bf16x8*)&nbuf[brow + 1024 + fo0];
    }
    __builtin_amdgcn_sched_barrier(0);
    __builtin_amdgcn_s_setprio(1);
#pragma unroll
    for (int i = 0; i < 8; ++i) { MFMA(acc[i][0], a1[i], Q0); MFMA(acc[i][1], a1[i], Q1); }
    __builtin_amdgcn_s_setprio(0);
    __builtin_amdgcn_s_barrier();
  }

  // ---- epilogue: C-write (col=lane&15, row=(lane>>4)*4+reg) ----
#pragma unroll
  for (int i = 0; i < 8; ++i)
#pragma unroll
    for (int j = 0; j < 4; ++j)
#pragma unroll
      for (int r = 0; r < 4; ++r)
        C[(long)(m0 + wm + i * 16 + lq * 4 + r) * N + n0 + wn + j * 16 + l16] = acc[i][j][r];
}

// ---------------- 256x128 bf16 GEMM, 3-buffer counted-vmcnt pipeline ----------------
// (byte-identical to round-7 gemm3b: ~90 us on the 256-block out-proj grid)
#define A3SZ 16384   // shorts: A panel (256 x 64)
#define T3SZ 24576   // shorts per buffer (A 32KB + B 16KB)

#define SA3(t) { short* d = &lds[((t) % 3) * T3SZ + dA]; const short* s = aS + (long)(t) * 64; \
                 gl2lds(s, d); gl2lds(s + K8, d + 512); gl2lds(s + 2 * K8, d + 1024); gl2lds(s + 3 * K8, d + 1536); }
#define SB3(t) { short* d = &lds[((t) % 3) * T3SZ + dB]; const short* s = bS + (long)(t) * 64; \
                 gl2lds(s, d); gl2lds(s + K8, d + 512); }

__global__ __launch_bounds__(512) void gemm3b(const short* __restrict__ A, const short* __restrict__ Bt,
                                              float* __restrict__ C, int M, int N, int K) {
  __shared__ __align__(16) short lds[3 * T3SZ];
  int nwg = gridDim.x;
  int lin = ((int)blockIdx.x & 7) * (nwg >> 3) + ((int)blockIdx.x >> 3);
  int mt = M >> 8;
  int m0 = (lin % mt) << 8, n0 = (lin / mt) << 7;

  int tid = threadIdx.x;
  int w = tid >> 6, lane = tid & 63;
  int l16 = lane & 15, lq = lane >> 4;
  int wm = (w >> 1) << 6;   // 0/64/128/192
  int wn = (w & 1) << 6;    // 0/64

  int s7 = l16 & 7;
  int fo0 = ((lq ^ s7) << 3);
  int fo1 = (((lq + 4) ^ s7) << 3);
  int arow = (wm + l16) * 64;           // + i*1024
  int brow = A3SZ + (wn + l16) * 64;    // + j*1024

  int srow = lane >> 3;
  int gch = (lane & 7) ^ srow;
  const short* aS = A + (long)(m0 + 32 * w + srow) * K + gch * 8;
  const short* bS = Bt + (long)(n0 + 16 * w + srow) * K + gch * 8;
  long K8 = 8L * K;
  int dA = w * 2048;            // 32w rows * 64 shorts
  int dB = A3SZ + w * 1024;     // 16w rows * 64 shorts

  f32x4 acc[4][4] = {};
  const int KT = K >> 6;

  SA3(0); SB3(0); SA3(1); SB3(1);
  asm volatile("s_waitcnt vmcnt(6)" ::: "memory");   // tile 0 landed; tile 1 in flight
  __builtin_amdgcn_s_barrier();

  for (int t = 0; t < KT; ++t) {
    const short* buf = &lds[(t % 3) * T3SZ];
    bool s2 = (t + 2 < KT);
    bf16x8 af[4], bfv[4];

    // ---- phase 1 (kk0): 8 reads ; stage A(t+2) ; 16 MFMA ----
#pragma unroll
    for (int i = 0; i < 4; ++i) af[i] = *(const bf16x8*)&buf[arow + i * 1024 + fo0];
#pragma unroll
    for (int j = 0; j < 4; ++j) bfv[j] = *(const bf16x8*)&buf[brow + j * 1024 + fo0];
    if (s2) SA3(t + 2);
    __builtin_amdgcn_s_barrier();
    asm volatile("s_waitcnt lgkmcnt(0)" ::: "memory");
    __builtin_amdgcn_s_setprio(1);
#pragma unroll
    for (int i = 0; i < 4; ++i)
#pragma unroll
      for (int j = 0; j < 4; ++j) MFMA(acc[i][j], af[i], bfv[j]);
    __builtin_amdgcn_s_setprio(0);
    __builtin_amdgcn_s_barrier();

    // ---- phase 2 (kk1): 8 reads ; stage B(t+2) ; 16 MFMA ; boundary vmcnt(6) ----
#pragma unroll
    for (int i = 0; i < 4; ++i) af[i] = *(const bf16x8*)&buf[arow + i * 1024 + fo1];
#pragma unroll
    for (int j = 0; j < 4; ++j) bfv[j] = *(const bf16x8*)&buf[brow + j * 1024 + fo1];
    if (s2) SB3(t + 2);
    __builtin_amdgcn_s_barrier();
    asm volatile("s_waitcnt lgkmcnt(0)" ::: "memory");
    __builtin_amdgcn_s_setprio(1);
#pragma unroll
    for (int i = 0; i < 4; ++i)
#pragma unroll
      for (int j = 0; j < 4; ++j) MFMA(acc[i][j], af[i], bfv[j]);
    __builtin_amdgcn_s_setprio(0);
    if (t + 1 < KT) {
      if (s2) asm volatile("s_waitcnt vmcnt(6)" ::: "memory");   // t+1 landed; t+2 in flight
      else    asm volatile("s_waitcnt vmcnt(0)" ::: "memory");   // last boundary: drain
      __builtin_amdgcn_s_barrier();
    }
  }

#pragma unroll
  for (int i = 0; i < 4; ++i)
#pragma unroll
    for (int j = 0; j < 4; ++j)
#pragma unroll
      for (int r = 0; r < 4; ++r)
        C[(long)(m0 + wm + i * 16 + lq * 4 + r) * N + n0 + wn + j * 16 + l16] = acc[i][j][r];
}

// ---------------- fused LayerNorm + RoPE ----------------
__global__ __launch_bounds__(64) void ln_rope(const float* __restrict__ qkv,
                                              const float* __restrict__ cosb, const float* __restrict__ sinb,
                                              const float* __restrict__ qw, const float* __restrict__ qb,
                                              const float* __restrict__ kw, const float* __restrict__ kb,
                                              short* __restrict__ qo, short* __restrict__ ko) {
  int s = blockIdx.x, slice = blockIdx.y, t = threadIdx.x;
  bool isq = slice < NH;
  int off = isq ? slice * HD : DIN + (slice - NH) * HD;
  const float* src = qkv + (long)s * NQKV + off;
  float v0 = src[t], v1 = src[t + 64];
  float sum = v0 + v1, ss = v0 * v0 + v1 * v1;
#pragma unroll
  for (int o = 1; o < 64; o <<= 1) { sum += __shfl_xor(sum, o); ss += __shfl_xor(ss, o); }
  float mu = sum * (1.f / 128.f);
  float var = ss * (1.f / 128.f) - mu * mu;
  float rstd = rsqrtf(var + 1e-6f);
  const float* w  = isq ? qw : kw;
  const float* bb = isq ? qb : kb;
  float n0 = (v0 - mu) * rstd * w[t]      + bb[t];
  float n1 = (v1 - mu) * rstd * w[t + 64] + bb[t + 64];
  float c0 = cosb[s * HD + t], c1 = cosb[s * HD + t + 64];
  float s0 = sinb[s * HD + t], s1 = sinb[s * HD + t + 64];
  float o0 = n0 * c0 - n1 * s0;
  float o1 = n1 * c1 + n0 * s1;
  short* dst = isq ? (qo + ((long)slice * SQ + s) * HD)
                   : (ko + ((long)(slice - NH) * SQ + s) * HD);
  dst[t] = f2bf(o0);
  dst[t + 64] = f2bf(o1);
}

// ---------------- flash attention, double-buffered K/V, causal-paired ----------------
__global__ __launch_bounds__(256) void attn(const short* __restrict__ q, const short* __restrict__ k,
                                            const short* __restrict__ vT, short* __restrict__ ctx) {
  int pair = blockIdx.x, h = blockIdx.y, g = h >> 2;
  int tid = threadIdx.x, w = tid >> 6, lane = tid & 63;
  int l16 = lane & 15, lq = lane >> 4;
  __shared__ __align__(16) short Ks[2][64 * 128];   // [key][128], chunk16 ^ (key&15)
  __shared__ __align__(16) short Vs[2][128 * 64];   // [d][64],    chunk8  ^ (d&7)
  __shared__ __align__(16) short pbuf[4][16 * 72];
  const short* qh = q + (long)h * SQ * HD;
  const short* kg = k + (long)g * SQ * HD;
  const short* vg = vT + (long)g * HD * SQ;
  int kr = (w * 4) * 4 + (lane >> 4);
  int vrw = (w * 4) * 8 + (lane >> 3);
  const float sc = 0.08838834764831845f * 1.4426950408889634f;  // 1/sqrt(128) * log2(e)

  for (int st = 0; st < 2; ++st) {
    int qt = st ? (31 - pair) : pair;
    int qbase = qt * 64 + w * 16;
    bf16x8 aq[4];
#pragma unroll
    for (int kk = 0; kk < 4; ++kk)
      aq[kk] = *(const bf16x8*)&qh[(long)(qbase + l16) * HD + kk * 32 + lq * 8];
    float m_r[4], l_r[4];
    f32x4 acc[8] = {};
#pragma unroll
    for (int r = 0; r < 4; ++r) { m_r[r] = -__builtin_inff(); l_r[r] = 0.f; }

#pragma unroll
    for (int j = 0; j < 4; ++j) {
      int call = w * 4 + j;
      int r = kr + j * 4;
      int chk = (lane & 15) ^ (r & 15);
      gl2lds(&kg[(long)r * HD + chk * 8], &Ks[0][call * 512]);
      int rv = vrw + j * 8;
      int chv = (lane & 7) ^ (rv & 7);
      gl2lds(&vg[(long)rv * SQ + chv * 8], &Vs[0][call * 512]);
    }

    for (int kt = 0; kt <= qt; ++kt) {
      int cur = kt & 1;
      bool more = kt < qt;
      if (more) {
#pragma unroll
        for (int j = 0; j < 4; ++j) {
          int call = w * 4 + j;
          int r = kr + j * 4;
          int chk = (lane & 15) ^ (r & 15);
          gl2lds(&kg[(long)((kt + 1) * 64 + r) * HD + chk * 8], &Ks[cur ^ 1][call * 512]);
          int rv = vrw + j * 8;
          int chv = (lane & 7) ^ (rv & 7);
          gl2lds(&vg[(long)rv * SQ + (kt + 1) * 64 + chv * 8], &Vs[cur ^ 1][call * 512]);
        }
        asm volatile("s_waitcnt vmcnt(8)" ::: "memory");
      } else {
        asm volatile("s_waitcnt vmcnt(0)" ::: "memory");
      }
      __builtin_amdgcn_s_barrier();

      f32x4 s4[4];
#pragma unroll
      for (int b = 0; b < 4; ++b) s4[b] = (f32x4){0.f, 0.f, 0.f, 0.f};
#pragma unroll
      for (int b = 0; b < 4; ++b) {
        int krow = b * 16 + l16;
#pragma unroll
        for (int kk = 0; kk < 4; ++kk) {
          bf16x8 bk = *(const bf16x8*)&Ks[cur][krow * 128 + ((kk * 4 + lq) ^ (krow & 15)) * 8];
          s4[b] = __builtin_amdgcn_mfma_f32_16x16x32_bf16(aq[kk], bk, s4[b], 0, 0, 0);
        }
      }
      int qrow0 = qbase + lq * 4;
      if (kt == qt) {
#pragma unroll
        for (int b = 0; b < 4; ++b) {
          int key = kt * 64 + b * 16 + l16;
#pragma unroll
          for (int r = 0; r < 4; ++r) {
            float val = s4[b][r] * sc;
            s4[b][r] = (key > qrow0 + r) ? -__builtin_inff() : val;
          }
        }
      } else {
#pragma unroll
        for (int b = 0; b < 4; ++b)
#pragma unroll
          for (int r = 0; r < 4; ++r) s4[b][r] *= sc;
      }
      float mx4[4];
      bool defer = true;
#pragma unroll
      for (int r = 0; r < 4; ++r) {
        float mx = fmaxf(fmaxf(s4[0][r], s4[1][r]), fmaxf(s4[2][r], s4[3][r]));
#pragma unroll
        for (int o = 1; o < 16; o <<= 1) mx = fmaxf(mx, __shfl_xor(mx, o));
        mx4[r] = mx;
        defer = defer && (mx - m_r[r] <= 8.f);
      }
      if (!__all((int)defer)) {
#pragma unroll
        for (int r = 0; r < 4; ++r) {
          float mnew = fmaxf(m_r[r], mx4[r]);
          float alpha = exp2f(m_r[r] - mnew);
          l_r[r] *= alpha;
          m_r[r] = mnew;
#pragma unroll
          for (int n = 0; n < 8; ++n) acc[n][r] *= alpha;
        }
      }
      float p[4][4];
#pragma unroll
      for (int r = 0; r < 4; ++r) {
        float sum = 0.f;
#pragma unroll
        for (int b = 0; b < 4; ++b) { float pv = exp2f(s4[b][r] - m_r[r]); p[b][r] = pv; sum += pv; }
#pragma unroll
        for (int o = 1; o < 16; o <<= 1) sum += __shfl_xor(sum, o);
        l_r[r] += sum;
      }
#pragma unroll
      for (int b = 0; b < 4; ++b)
#pragma unroll
        for (int r = 0; r < 4; ++r)
          pbuf[w][(lq * 4 + r) * 72 + b * 16 + l16] = f2bf(p[b][r]);
#pragma unroll
      for (int kk = 0; kk < 2; ++kk) {
        bf16x8 pf = *(const bf16x8*)&pbuf[w][l16 * 72 + kk * 32 + lq * 8];
#pragma unroll
        for (int n = 0; n < 8; ++n) {
          int vrow = n * 16 + l16;
          bf16x8 vf = *(const bf16x8*)&Vs[cur][vrow * 64 + ((kk * 4 + lq) ^ (vrow & 7)) * 8];
          acc[n] = __builtin_amdgcn_mfma_f32_16x16x32_bf16(pf, vf, acc[n], 0, 0, 0);
        }
      }
      __builtin_amdgcn_s_barrier();
    }
#pragma unroll
    for (int n = 0; n < 8; ++n)
#pragma unroll
      for (int r = 0; r < 4; ++r) {
        int srow = qbase + lq * 4 + r;
        ctx[(long)srow * (NH * HD) + h * HD + n * 16 + l16] = f2bf(acc[n][r] / l_r[r]);
      }
  }
}

// ---------------- workspace layout ----------------
#define XB_OFF     0L
#define QR_OFF     0L
#define WQKVT_OFF  16777216L
#define KR_OFF     16777216L
#define VT_OFF     20971520L
#define CTX_OFF    25165824L
#define WOT_OFF    67108864L
#define QKV_OFF    100663296L

extern "C" void kernel_launch(void* const* d_in, const int* in_sizes, int n_in,
                              void* d_out, int out_size, void* d_ws, size_t ws_size,
                              hipStream_t stream) {
  const float* x    = (const float*)d_in[0];
  const float* cosb = (const float*)d_in[2];
  const float* sinb = (const float*)d_in[3];
  const float* Wq   = (const float*)d_in[4];
  const float* Wk   = (const float*)d_in[5];
  const float* Wv   = (const float*)d_in[6];
  const float* Wo   = (const float*)d_in[7];
  const float* qnw  = (const float*)d_in[8];
  const float* qnb  = (const float*)d_in[9];
  const float* knw  = (const float*)d_in[10];
  const float* knb  = (const float*)d_in[11];

  char* ws = (char*)d_ws;
  short* xb    = (short*)(ws + XB_OFF);
  short* qr    = (short*)(ws + QR_OFF);
  short* wqkvt = (short*)(ws + WQKVT_OFF);
  short* krp   = (short*)(ws + KR_OFF);
  short* vt    = (short*)(ws + VT_OFF);
  short* ctx   = (short*)(ws + CTX_OFF);
  short* wot   = (short*)(ws + WOT_OFF);
  float* qkv   = (float*)(ws + QKV_OFF);

  cvt_bf16<<<8192, 256, 0, stream>>>(x, xb, (long)SQ * DIN);
  transpose_cvt<<<dim3(64, 64, 1), 256, 0, stream>>>(Wq, 4096, 0L, wqkvt, 4096, 0L);
  transpose_cvt<<<dim3(16, 64, 1), 256, 0, stream>>>(Wk, 1024, 0L, wqkvt + (long)4096 * 4096, 4096, 0L);
  transpose_cvt<<<dim3(16, 64, 1), 256, 0, stream>>>(Wv, 1024, 0L, wqkvt + (long)5120 * 4096, 4096, 0L);
  transpose_cvt<<<dim3(64, 64, 1), 256, 0, stream>>>(Wo, 4096, 0L, wot, 4096, 0L);
  gemm8p<<<(SQ / 256) * (NQKV / 256), 512, 0, stream>>>(xb, wqkvt, qkv, SQ, NQKV, DIN);
  ln_rope<<<dim3(SQ, NH + NKV), 64, 0, stream>>>(qkv, cosb, sinb, qnw, qnb, knw, knb, qr, krp);
  transpose_cvt<<<dim3(2, 32, 8), 256, 0, stream>>>(qkv + 5120, NQKV, 128L, vt, SQ, (long)HD * SQ);
  attn<<<dim3(16, NH), 256, 0, stream>>>(qr, krp, vt, ctx);
  gemm3b<<<(SQ / 256) * (DIN / 128), 512, 0, stream>>>(ctx, wot, (float*)d_out, SQ, DIN, DIN);
}

// Round 10
// 535.956 us; speedup vs baseline: 1.1494x; 1.0077x over previous
//
#include <hip/hip_runtime.h>
#include <stdint.h>

#define SQ   2048
#define DIN  4096
#define NH   32
#define NKV  8
#define HD   128
#define NQKV 6144

typedef float f32x4 __attribute__((ext_vector_type(4)));
typedef short bf16x8 __attribute__((ext_vector_type(8)));

__device__ __forceinline__ short f2bf(float f) {
  union { float f; uint32_t u; } v; v.f = f;
  uint32_t r = (v.u + 0x7FFFu + ((v.u >> 16) & 1u)) >> 16;
  return (short)r;
}

// async global -> LDS, 16 bytes per lane, dst = lds_base + lane*16 (HW-fixed)
__device__ __forceinline__ void gl2lds(const void* g, void* l) {
  __builtin_amdgcn_global_load_lds(
      (const __attribute__((address_space(1))) void*)g,
      (__attribute__((address_space(3))) void*)l, 16, 0, 0);
}

// ---------------- fp32 -> bf16 elementwise convert ----------------
__global__ void cvt_bf16(const float* __restrict__ src, short* __restrict__ dst, long n) {
  long i = ((long)blockIdx.x * blockDim.x + threadIdx.x) * 4;
  if (i + 3 < n) {
    float4 v = *(const float4*)(src + i);
    short o[4] = { f2bf(v.x), f2bf(v.y), f2bf(v.z), f2bf(v.w) };
    *(uint2*)(dst + i) = *(uint2*)o;
  }
}

// ---------------- tiled transpose + convert: dst[c][r] = src[r][c] ----------------
// Vectorized: float4 global loads (16 B/lane), ushort4 stores (8 B/lane).
// LDS tile[64][65]: scalar accesses, banks spread 2-way (free, m136).
__global__ __launch_bounds__(256) void transpose_cvt(const float* __restrict__ src, int ldS, long zS,
                                                     short* __restrict__ dst, int ldD, long zD) {
  __shared__ float tile[64][65];
  src += (long)blockIdx.z * zS;
  dst += (long)blockIdx.z * zD;
  int r0 = blockIdx.y * 64, c0 = blockIdx.x * 64;
  int tid = threadIdx.x;
#pragma unroll
  for (int i = 0; i < 4; ++i) {
    int idx = i * 256 + tid;            // 1024 = 64 rows x 16 col-quads
    int rr = idx >> 4, c4 = (idx & 15) * 4;
    float4 v = *(const float4*)&src[(long)(r0 + rr) * ldS + c0 + c4];
    tile[rr][c4 + 0] = v.x; tile[rr][c4 + 1] = v.y;
    tile[rr][c4 + 2] = v.z; tile[rr][c4 + 3] = v.w;
  }
  __syncthreads();
#pragma unroll
  for (int i = 0; i < 4; ++i) {
    int idx = i * 256 + tid;            // 1024 = 64 dst-rows x 16 row-quads
    int cc = idx >> 4, r4 = (idx & 15) * 4;
    short o[4];
#pragma unroll
    for (int j = 0; j < 4; ++j) o[j] = f2bf(tile[r4 + j][cc]);
    *(uint2*)&dst[(long)(c0 + cc) * ldD + r0 + r4] = *(uint2*)o;
  }
}

// ---------------- 256x256 bf16 GEMM, read-ahead pipelined (sentinel) ----------------
#define ASZ   16384   // shorts: A panel per buffer (256 rows x 64)
#define BUFSZ 32768   // shorts per buffer (A + B)
#define MFMA(d, a, b) d = __builtin_amdgcn_mfma_f32_16x16x32_bf16(a, b, d, 0, 0, 0)

#define SA(t) { short* d = &lds[(((t) & 1) * BUFSZ) + dA]; const short* s = aS + (long)(t) * 64; \
                gl2lds(s, d); gl2lds(s + K8, d + 512); gl2lds(s + 2 * K8, d + 1024); gl2lds(s + 3 * K8, d + 1536); }
#define SB(t) { short* d = &lds[(((t) & 1) * BUFSZ) + dB]; const short* s = bS + (long)(t) * 64; \
                gl2lds(s, d); gl2lds(s + K8, d + 512); gl2lds(s + 2 * K8, d + 1024); gl2lds(s + 3 * K8, d + 1536); }

__global__ __launch_bounds__(512, 2) void gemm8p(const short* __restrict__ A, const short* __restrict__ Bt,
                                                 float* __restrict__ C, int M, int N, int K) {
  __shared__ __align__(16) short lds[2 * BUFSZ];
  int nwg = gridDim.x;
  int lin = ((int)blockIdx.x & 7) * (nwg >> 3) + ((int)blockIdx.x >> 3);
  int mt = M >> 8;
  int m0 = (lin % mt) << 8, n0 = (lin / mt) << 8;

  int tid = threadIdx.x;
  int w = tid >> 6, lane = tid & 63;
  int l16 = lane & 15, lq = lane >> 4;
  int wm = (w >> 2) << 7;   // 0 / 128
  int wn = (w & 3) << 6;    // 0 / 64 / 128 / 192

  int s7 = l16 & 7;
  int fo0 = ((lq ^ s7) << 3);          // kk0
  int fo1 = (((lq + 4) ^ s7) << 3);    // kk1
  int arow = (wm + l16) * 64;          // + i*1024
  int brow = ASZ + (wn + l16) * 64;    // + j*1024

  int srow = lane >> 3;
  int gch = (lane & 7) ^ srow;
  const short* aS = A + (long)(m0 + 32 * w + srow) * K + gch * 8;
  const short* bS = Bt + (long)(n0 + 32 * w + srow) * K + gch * 8;
  long K8 = 8L * K;
  int dA = (32 * w) * 64;
  int dB = ASZ + (32 * w) * 64;

  f32x4 acc[8][4] = {};
  bf16x8 a0[8], a1[8], P0, P1, Q0, Q1;
  const int KT = K >> 6;

  SA(0); SB(0);
  asm volatile("s_waitcnt vmcnt(0)" ::: "memory");
  __builtin_amdgcn_s_barrier();
  {
    const short* buf = &lds[0];
#pragma unroll
    for (int i = 0; i < 8; ++i) a0[i] = *(const bf16x8*)&buf[arow + i * 1024 + fo0];
    P0 = *(const bf16x8*)&buf[brow + fo0];
    P1 = *(const bf16x8*)&buf[brow + 1024 + fo0];
  }

  for (int t = 0; t < KT; ++t) {
    const short* buf  = &lds[(t & 1) * BUFSZ];
    const short* nbuf = &lds[((t + 1) & 1) * BUFSZ];
    bool s1 = (t + 1 < KT);

    // ---- seg1: read kk0-j23 ; stage A(t+1) ; MFMA a0 x kk0-j01 ----
    Q0 = *(const bf16x8*)&buf[brow + 2048 + fo0];
    Q1 = *(const bf16x8*)&buf[brow + 3072 + fo0];
    if (s1) SA(t + 1);
    __builtin_amdgcn_sched_barrier(0);
    __builtin_amdgcn_s_setprio(1);
#pragma unroll
    for (int i = 0; i < 8; ++i) { MFMA(acc[i][0], a0[i], P0); MFMA(acc[i][1], a0[i], P1); }
    __builtin_amdgcn_s_setprio(0);
    __builtin_amdgcn_s_barrier();

    // ---- seg2: read A-kk1 + kk1-j23 ; stage B(t+1) ; MFMA a0 x kk0-j23 ----
#pragma unroll
    for (int i = 0; i < 8; ++i) a1[i] = *(const bf16x8*)&buf[arow + i * 1024 + fo1];
    P0 = *(const bf16x8*)&buf[brow + 2048 + fo1];
    P1 = *(const bf16x8*)&buf[brow + 3072 + fo1];
    if (s1) SB(t + 1);
    __builtin_amdgcn_sched_barrier(0);
    __builtin_amdgcn_s_setprio(1);
#pragma unroll
    for (int i = 0; i < 8; ++i) { MFMA(acc[i][2], a0[i], Q0); MFMA(acc[i][3], a0[i], Q1); }
    __builtin_amdgcn_s_setprio(0);
    __builtin_amdgcn_s_barrier();

    // ---- seg3: read kk1-j01 ; MFMA a1 x kk1-j23 ; boundary vmcnt+barrier ----
    Q0 = *(const bf16x8*)&buf[brow + fo1];
    Q1 = *(const bf16x8*)&buf[brow + 1024 + fo1];
    __builtin_amdgcn_sched_barrier(0);
    __builtin_amdgcn_s_setprio(1);
#pragma unroll
    for (int i = 0; i < 8; ++i) { MFMA(acc[i][2], a1[i], P0); MFMA(acc[i][3], a1[i], P1); }
    __builtin_amdgcn_s_setprio(0);
    if (s1) asm volatile("s_waitcnt vmcnt(0)" ::: "memory");
    __builtin_amdgcn_s_barrier();

    // ---- seg4: read next tile's kk0 set from fresh buffer ; MFMA a1 x kk1-j01 ----
    if (s1) {
#pragma unroll
      for (int i = 0; i < 8; ++i) a0[i] = *(const bf16x8*)&nbuf[arow + i * 1024 + fo0];
      P0 = *(const bf16x8*)&nbuf[brow + fo0];
      P1 = *(const bf16x8*)&nbuf[brow + 1024 + fo0];
    }
    __builtin_amdgcn_sched_barrier(0);
    __builtin_amdgcn_s_setprio(1);
#pragma unroll
    for (int i = 0; i < 8; ++i) { MFMA(acc[i][0], a1[i], Q0); MFMA(acc[i][1], a1[i], Q1); }
    __builtin_amdgcn_s_setprio(0);
    __builtin_amdgcn_s_barrier();
  }

#pragma unroll
  for (int i = 0; i < 8; ++i)
#pragma unroll
    for (int j = 0; j < 4; ++j)
#pragma unroll
      for (int r = 0; r < 4; ++r)
        C[(long)(m0 + wm + i * 16 + lq * 4 + r) * N + n0 + wn + j * 16 + l16] = acc[i][j][r];
}

// ---------------- 256x128 bf16 GEMM, 3-buffer counted-vmcnt pipeline (sentinel) ----------------
#define A3SZ 16384   // shorts: A panel (256 x 64)
#define T3SZ 24576   // shorts per buffer (A 32KB + B 16KB)

#define SA3(t) { short* d = &lds[((t) % 3) * T3SZ + dA]; const short* s = aS + (long)(t) * 64; \
                 gl2lds(s, d); gl2lds(s + K8, d + 512); gl2lds(s + 2 * K8, d + 1024); gl2lds(s + 3 * K8, d + 1536); }
#define SB3(t) { short* d = &lds[((t) % 3) * T3SZ + dB]; const short* s = bS + (long)(t) * 64; \
                 gl2lds(s, d); gl2lds(s + K8, d + 512); }

__global__ __launch_bounds__(512) void gemm3b(const short* __restrict__ A, const short* __restrict__ Bt,
                                              float* __restrict__ C, int M, int N, int K) {
  __shared__ __align__(16) short lds[3 * T3SZ];
  int nwg = gridDim.x;
  int lin = ((int)blockIdx.x & 7) * (nwg >> 3) + ((int)blockIdx.x >> 3);
  int mt = M >> 8;
  int m0 = (lin % mt) << 8, n0 = (lin / mt) << 7;

  int tid = threadIdx.x;
  int w = tid >> 6, lane = tid & 63;
  int l16 = lane & 15, lq = lane >> 4;
  int wm = (w >> 1) << 6;   // 0/64/128/192
  int wn = (w & 1) << 6;    // 0/64

  int s7 = l16 & 7;
  int fo0 = ((lq ^ s7) << 3);
  int fo1 = (((lq + 4) ^ s7) << 3);
  int arow = (wm + l16) * 64;           // + i*1024
  int brow = A3SZ + (wn + l16) * 64;    // + j*1024

  int srow = lane >> 3;
  int gch = (lane & 7) ^ srow;
  const short* aS = A + (long)(m0 + 32 * w + srow) * K + gch * 8;
  const short* bS = Bt + (long)(n0 + 16 * w + srow) * K + gch * 8;
  long K8 = 8L * K;
  int dA = w * 2048;            // 32w rows * 64 shorts
  int dB = A3SZ + w * 1024;     // 16w rows * 64 shorts

  f32x4 acc[4][4] = {};
  const int KT = K >> 6;

  SA3(0); SB3(0); SA3(1); SB3(1);
  asm volatile("s_waitcnt vmcnt(6)" ::: "memory");
  __builtin_amdgcn_s_barrier();

  for (int t = 0; t < KT; ++t) {
    const short* buf = &lds[(t % 3) * T3SZ];
    bool s2 = (t + 2 < KT);
    bf16x8 af[4], bfv[4];

    // ---- phase 1 (kk0): 8 reads ; stage A(t+2) ; 16 MFMA ----
#pragma unroll
    for (int i = 0; i < 4; ++i) af[i] = *(const bf16x8*)&buf[arow + i * 1024 + fo0];
#pragma unroll
    for (int j = 0; j < 4; ++j) bfv[j] = *(const bf16x8*)&buf[brow + j * 1024 + fo0];
    if (s2) SA3(t + 2);
    __builtin_amdgcn_s_barrier();
    asm volatile("s_waitcnt lgkmcnt(0)" ::: "memory");
    __builtin_amdgcn_s_setprio(1);
#pragma unroll
    for (int i = 0; i < 4; ++i)
#pragma unroll
      for (int j = 0; j < 4; ++j) MFMA(acc[i][j], af[i], bfv[j]);
    __builtin_amdgcn_s_setprio(0);
    __builtin_amdgcn_s_barrier();

    // ---- phase 2 (kk1): 8 reads ; stage B(t+2) ; 16 MFMA ; boundary vmcnt(6) ----
#pragma unroll
    for (int i = 0; i < 4; ++i) af[i] = *(const bf16x8*)&buf[arow + i * 1024 + fo1];
#pragma unroll
    for (int j = 0; j < 4; ++j) bfv[j] = *(const bf16x8*)&buf[brow + j * 1024 + fo1];
    if (s2) SB3(t + 2);
    __builtin_amdgcn_s_barrier();
    asm volatile("s_waitcnt lgkmcnt(0)" ::: "memory");
    __builtin_amdgcn_s_setprio(1);
#pragma unroll
    for (int i = 0; i < 4; ++i)
#pragma unroll
      for (int j = 0; j < 4; ++j) MFMA(acc[i][j], af[i], bfv[j]);
    __builtin_amdgcn_s_setprio(0);
    if (t + 1 < KT) {
      if (s2) asm volatile("s_waitcnt vmcnt(6)" ::: "memory");
      else    asm volatile("s_waitcnt vmcnt(0)" ::: "memory");
      __builtin_amdgcn_s_barrier();
    }
  }

#pragma unroll
  for (int i = 0; i < 4; ++i)
#pragma unroll
    for (int j = 0; j < 4; ++j)
#pragma unroll
      for (int r = 0; r < 4; ++r)
        C[(long)(m0 + wm + i * 16 + lq * 4 + r) * N + n0 + wn + j * 16 + l16] = acc[i][j][r];
}

// ---------------- fused LayerNorm + RoPE ----------------
__global__ __launch_bounds__(64) void ln_rope(const float* __restrict__ qkv,
                                              const float* __restrict__ cosb, const float* __restrict__ sinb,
                                              const float* __restrict__ qw, const float* __restrict__ qb,
                                              const float* __restrict__ kw, const float* __restrict__ kb,
                                              short* __restrict__ qo, short* __restrict__ ko) {
  int s = blockIdx.x, slice = blockIdx.y, t = threadIdx.x;
  bool isq = slice < NH;
  int off = isq ? slice * HD : DIN + (slice - NH) * HD;
  const float* src = qkv + (long)s * NQKV + off;
  float v0 = src[t], v1 = src[t + 64];
  float sum = v0 + v1, ss = v0 * v0 + v1 * v1;
#pragma unroll
  for (int o = 1; o < 64; o <<= 1) { sum += __shfl_xor(sum, o); ss += __shfl_xor(ss, o); }
  float mu = sum * (1.f / 128.f);
  float var = ss * (1.f / 128.f) - mu * mu;
  float rstd = rsqrtf(var + 1e-6f);
  const float* w  = isq ? qw : kw;
  const float* bb = isq ? qb : kb;
  float n0 = (v0 - mu) * rstd * w[t]      + bb[t];
  float n1 = (v1 - mu) * rstd * w[t + 64] + bb[t + 64];
  float c0 = cosb[s * HD + t], c1 = cosb[s * HD + t + 64];
  float s0 = sinb[s * HD + t], s1 = sinb[s * HD + t + 64];
  float o0 = n0 * c0 - n1 * s0;
  float o1 = n1 * c1 + n0 * s1;
  short* dst = isq ? (qo + ((long)slice * SQ + s) * HD)
                   : (ko + ((long)(slice - NH) * SQ + s) * HD);
  dst[t] = f2bf(o0);
  dst[t + 64] = f2bf(o1);
}

// ---------------- flash attention, double-buffered K/V, causal-paired ----------------
// + s_setprio(1) around QK^T and PV MFMA clusters (T5; 2 independent blocks/CU
// give the scheduler cross-block wave diversity to arbitrate).
__global__ __launch_bounds__(256) void attn(const short* __restrict__ q, const short* __restrict__ k,
                                            const short* __restrict__ vT, short* __restrict__ ctx) {
  int pair = blockIdx.x, h = blockIdx.y, g = h >> 2;
  int tid = threadIdx.x, w = tid >> 6, lane = tid & 63;
  int l16 = lane & 15, lq = lane >> 4;
  __shared__ __align__(16) short Ks[2][64 * 128];   // [key][128], chunk16 ^ (key&15)
  __shared__ __align__(16) short Vs[2][128 * 64];   // [d][64],    chunk8  ^ (d&7)
  __shared__ __align__(16) short pbuf[4][16 * 72];
  const short* qh = q + (long)h * SQ * HD;
  const short* kg = k + (long)g * SQ * HD;
  const short* vg = vT + (long)g * HD * SQ;
  int kr = (w * 4) * 4 + (lane >> 4);
  int vrw = (w * 4) * 8 + (lane >> 3);
  const float sc = 0.08838834764831845f * 1.4426950408889634f;  // 1/sqrt(128) * log2(e)

  for (int st = 0; st < 2; ++st) {
    int qt = st ? (31 - pair) : pair;
    int qbase = qt * 64 + w * 16;
    bf16x8 aq[4];
#pragma unroll
    for (int kk = 0; kk < 4; ++kk)
      aq[kk] = *(const bf16x8*)&qh[(long)(qbase + l16) * HD + kk * 32 + lq * 8];
    float m_r[4], l_r[4];
    f32x4 acc[8] = {};
#pragma unroll
    for (int r = 0; r < 4; ++r) { m_r[r] = -__builtin_inff(); l_r[r] = 0.f; }

#pragma unroll
    for (int j = 0; j < 4; ++j) {
      int call = w * 4 + j;
      int r = kr + j * 4;
      int chk = (lane & 15) ^ (r & 15);
      gl2lds(&kg[(long)r * HD + chk * 8], &Ks[0][call * 512]);
      int rv = vrw + j * 8;
      int chv = (lane & 7) ^ (rv & 7);
      gl2lds(&vg[(long)rv * SQ + chv * 8], &Vs[0][call * 512]);
    }

    for (int kt = 0; kt <= qt; ++kt) {
      int cur = kt & 1;
      bool more = kt < qt;
      if (more) {
#pragma unroll
        for (int j = 0; j < 4; ++j) {
          int call = w * 4 + j;
          int r = kr + j * 4;
          int chk = (lane & 15) ^ (r & 15);
          gl2lds(&kg[(long)((kt + 1) * 64 + r) * HD + chk * 8], &Ks[cur ^ 1][call * 512]);
          int rv = vrw + j * 8;
          int chv = (lane & 7) ^ (rv & 7);
          gl2lds(&vg[(long)rv * SQ + (kt + 1) * 64 + chv * 8], &Vs[cur ^ 1][call * 512]);
        }
        asm volatile("s_waitcnt vmcnt(8)" ::: "memory");
      } else {
        asm volatile("s_waitcnt vmcnt(0)" ::: "memory");
      }
      __builtin_amdgcn_s_barrier();

      f32x4 s4[4];
#pragma unroll
      for (int b = 0; b < 4; ++b) s4[b] = (f32x4){0.f, 0.f, 0.f, 0.f};
      __builtin_amdgcn_s_setprio(1);
#pragma unroll
      for (int b = 0; b < 4; ++b) {
        int krow = b * 16 + l16;
#pragma unroll
        for (int kk = 0; kk < 4; ++kk) {
          bf16x8 bk = *(const bf16x8*)&Ks[cur][krow * 128 + ((kk * 4 + lq) ^ (krow & 15)) * 8];
          s4[b] = __builtin_amdgcn_mfma_f32_16x16x32_bf16(aq[kk], bk, s4[b], 0, 0, 0);
        }
      }
      __builtin_amdgcn_s_setprio(0);
      int qrow0 = qbase + lq * 4;
      if (kt == qt) {
#pragma unroll
        for (int b = 0; b < 4; ++b) {
          int key = kt * 64 + b * 16 + l16;
#pragma unroll
          for (int r = 0; r < 4; ++r) {
            float val = s4[b][r] * sc;
            s4[b][r] = (key > qrow0 + r) ? -__builtin_inff() : val;
          }
        }
      } else {
#pragma unroll
        for (int b = 0; b < 4; ++b)
#pragma unroll
          for (int r = 0; r < 4; ++r) s4[b][r] *= sc;
      }
      float mx4[4];
      bool defer = true;
#pragma unroll
      for (int r = 0; r < 4; ++r) {
        float mx = fmaxf(fmaxf(s4[0][r], s4[1][r]), fmaxf(s4[2][r], s4[3][r]));
#pragma unroll
        for (int o = 1; o < 16; o <<= 1) mx = fmaxf(mx, __shfl_xor(mx, o));
        mx4[r] = mx;
        defer = defer && (mx - m_r[r] <= 8.f);
      }
      if (!__all((int)defer)) {
#pragma unroll
        for (int r = 0; r < 4; ++r) {
          float mnew = fmaxf(m_r[r], mx4[r]);
          float alpha = exp2f(m_r[r] - mnew);
          l_r[r] *= alpha;
          m_r[r] = mnew;
#pragma unroll
          for (int n = 0; n < 8; ++n) acc[n][r] *= alpha;
        }
      }
      float p[4][4];
#pragma unroll
      for (int r = 0; r < 4; ++r) {
        float sum = 0.f;
#pragma unroll
        for (int b = 0; b < 4; ++b) { float pv = exp2f(s4[b][r] - m_r[r]); p[b][r] = pv; sum += pv; }
#pragma unroll
        for (int o = 1; o < 16; o <<= 1) sum += __shfl_xor(sum, o);
        l_r[r] += sum;
      }
#pragma unroll
      for (int b = 0; b < 4; ++b)
#pragma unroll
        for (int r = 0; r < 4; ++r)
          pbuf[w][(lq * 4 + r) * 72 + b * 16 + l16] = f2bf(p[b][r]);
      __builtin_amdgcn_s_setprio(1);
#pragma unroll
      for (int kk = 0; kk < 2; ++kk) {
        bf16x8 pf = *(const bf16x8*)&pbuf[w][l16 * 72 + kk * 32 + lq * 8];
#pragma unroll
        for (int n = 0; n < 8; ++n) {
          int vrow = n * 16 + l16;
          bf16x8 vf = *(const bf16x8*)&Vs[cur][vrow * 64 + ((kk * 4 + lq) ^ (vrow & 7)) * 8];
          acc[n] = __builtin_amdgcn_mfma_f32_16x16x32_bf16(pf, vf, acc[n], 0, 0, 0);
        }
      }
      __builtin_amdgcn_s_setprio(0);
      __builtin_amdgcn_s_barrier();
    }
#pragma unroll
    for (int n = 0; n < 8; ++n)
#pragma unroll
      for (int r = 0; r < 4; ++r) {
        int srow = qbase + lq * 4 + r;
        ctx[(long)srow * (NH * HD) + h * HD + n * 16 + l16] = f2bf(acc[n][r] / l_r[r]);
      }
  }
}

// ---------------- workspace layout ----------------
#define XB_OFF     0L
#define QR_OFF     0L
#define WQKVT_OFF  16777216L
#define KR_OFF     16777216L
#define VT_OFF     20971520L
#define CTX_OFF    25165824L
#define WOT_OFF    67108864L
#define QKV_OFF    100663296L

extern "C" void kernel_launch(void* const* d_in, const int* in_sizes, int n_in,
                              void* d_out, int out_size, void* d_ws, size_t ws_size,
                              hipStream_t stream) {
  const float* x    = (const float*)d_in[0];
  const float* cosb = (const float*)d_in[2];
  const float* sinb = (const float*)d_in[3];
  const float* Wq   = (const float*)d_in[4];
  const float* Wk   = (const float*)d_in[5];
  const float* Wv   = (const float*)d_in[6];
  const float* Wo   = (const float*)d_in[7];
  const float* qnw  = (const float*)d_in[8];
  const float* qnb  = (const float*)d_in[9];
  const float* knw  = (const float*)d_in[10];
  const float* knb  = (const float*)d_in[11];

  char* ws = (char*)d_ws;
  short* xb    = (short*)(ws + XB_OFF);
  short* qr    = (short*)(ws + QR_OFF);
  short* wqkvt = (short*)(ws + WQKVT_OFF);
  short* krp   = (short*)(ws + KR_OFF);
  short* vt    = (short*)(ws + VT_OFF);
  short* ctx   = (short*)(ws + CTX_OFF);
  short* wot   = (short*)(ws + WOT_OFF);
  float* qkv   = (float*)(ws + QKV_OFF);

  cvt_bf16<<<8192, 256, 0, stream>>>(x, xb, (long)SQ * DIN);
  transpose_cvt<<<dim3(64, 64, 1), 256, 0, stream>>>(Wq, 4096, 0L, wqkvt, 4096, 0L);
  transpose_cvt<<<dim3(16, 64, 1), 256, 0, stream>>>(Wk, 1024, 0L, wqkvt + (long)4096 * 4096, 4096, 0L);
  transpose_cvt<<<dim3(16, 64, 1), 256, 0, stream>>>(Wv, 1024, 0L, wqkvt + (long)5120 * 4096, 4096, 0L);
  transpose_cvt<<<dim3(64, 64, 1), 256, 0, stream>>>(Wo, 4096, 0L, wot, 4096, 0L);
  gemm8p<<<(SQ / 256) * (NQKV / 256), 512, 0, stream>>>(xb, wqkvt, qkv, SQ, NQKV, DIN);
  ln_rope<<<dim3(SQ, NH + NKV), 64, 0, stream>>>(qkv, cosb, sinb, qnw, qnb, knw, knb, qr, krp);
  transpose_cvt<<<dim3(2, 32, 8), 256, 0, stream>>>(qkv + 5120, NQKV, 128L, vt, SQ, (long)HD * SQ);
  attn<<<dim3(16, NH), 256, 0, stream>>>(qr, krp, vt, ctx);
  gemm3b<<<(SQ / 256) * (DIN / 128), 512, 0, stream>>>(ctx, wot, (float*)d_out, SQ, DIN, DIN);
}